// Round 5
// baseline (4596.920 us; speedup 1.0000x reference)
//
#include <hip/hip_runtime.h>
#include <math.h>

#define T_ 64
#define B_ 256
#define N_ 256
#define M_ 128
#define H_ 1024
#define I_ 128
#define NB 256
#define NT 1024
#define MSTR 132          // mem row stride (floats)
#define EPSF 1e-8f

// ---- ws layout (uint offsets). Big weights THREAD-MAJOR [k-chunk][col]:
// consecutive lanes read consecutive 16B -> coalesced wave transactions. ----
#define WS_WCX 0                 // [16 k4][1024 h] uint4  (Wc x-part)
#define WS_WCR 65536             // [16 k4][1024 h] uint4  (Wc rd-part)
#define WS_W2P 131072            // [128 k4][512 c] uint4  (Wk0|Wk1|We|Wa)
#define WS_WOP 393216            // [16 k4][128 c]  uint4  (Wo)
#define WS_WSM 401408            // [12 d][512 k2]  uint   (beta,g,gamma,shift)
#define WS_XC  407552            // _Float16 xc[T*B][H] (32 MB)
#define WS_BYTES_NEEDED ((size_t)(407552 + 8388608) * 4)

typedef _Float16 h2_t __attribute__((ext_vector_type(2)));

__device__ __forceinline__ float fdot2(unsigned a, unsigned b, float c) {
  union { unsigned u; h2_t h; } ua, ub;
  ua.u = a; ub.u = b;
  return __builtin_amdgcn_fdot2(ua.h, ub.h, c, false);
}
__device__ __forceinline__ unsigned packh2(float a, float b) {
  union { h2_t h; unsigned u; } v;
  v.h = h2_t{(_Float16)a, (_Float16)b};
  return v.u;
}
__device__ __forceinline__ float dot4(uint4 w, uint4 h, float acc) {
  acc = fdot2(w.x, h.x, acc); acc = fdot2(w.y, h.y, acc);
  acc = fdot2(w.z, h.z, acc); acc = fdot2(w.w, h.w, acc);
  return acc;
}
__device__ __forceinline__ float wave_rsum(float v) {
#pragma unroll
  for (int o = 32; o > 0; o >>= 1) v += __shfl_xor(v, o, 64);
  return v;
}
__device__ __forceinline__ float wave_rmax(float v) {
#pragma unroll
  for (int o = 32; o > 0; o >>= 1) v = fmaxf(v, __shfl_xor(v, o, 64));
  return v;
}

// ============ pack: fp32 -> fp16, thread-major chunked layouts ============
__global__ void ntm_pack(const float* __restrict__ Wc, const float* __restrict__ Wk,
                         const float* __restrict__ Wb, const float* __restrict__ Wg,
                         const float* __restrict__ Wsf, const float* __restrict__ Wgm,
                         const float* __restrict__ We, const float* __restrict__ Wa,
                         const float* __restrict__ Wo,
                         unsigned* __restrict__ wsu)
{
  const int total = 407552;
  for (int i = blockIdx.x * blockDim.x + threadIdx.x; i < total;
       i += gridDim.x * blockDim.x) {
    if (i < 65536) {                       // WCX: q4 = k4*1024 + h
      int jm = i & 3, q4 = i >> 2, k4 = q4 >> 10, h = q4 & 1023;
      int k0 = k4 * 8 + 2 * jm;
      wsu[WS_WCX + i] = packh2(Wc[(size_t)k0 * H_ + h], Wc[(size_t)(k0 + 1) * H_ + h]);
    } else if (i < 131072) {               // WCR: rd-part rows 128..255
      int u = i - 65536;
      int jm = u & 3, q4 = u >> 2, k4 = q4 >> 10, h = q4 & 1023;
      int k0 = 128 + k4 * 8 + 2 * jm;
      wsu[WS_WCR + u] = packh2(Wc[(size_t)k0 * H_ + h], Wc[(size_t)(k0 + 1) * H_ + h]);
    } else if (i < 393216) {               // W2P: q4 = k4*512 + c
      int u = i - 131072;
      int jm = u & 3, q4 = u >> 2, k4 = q4 >> 9, c = q4 & 511;
      int k0 = k4 * 8 + 2 * jm, k1 = k0 + 1;
      float v0, v1;
      if (c < 128)      { v0 = Wk[(size_t)k0 * M_ + c];           v1 = Wk[(size_t)k1 * M_ + c]; }
      else if (c < 256) { v0 = Wk[(size_t)H_ * M_ + (size_t)k0 * M_ + (c - 128)];
                          v1 = Wk[(size_t)H_ * M_ + (size_t)k1 * M_ + (c - 128)]; }
      else if (c < 384) { v0 = We[(size_t)k0 * M_ + (c - 256)];   v1 = We[(size_t)k1 * M_ + (c - 256)]; }
      else              { v0 = Wa[(size_t)k0 * M_ + (c - 384)];   v1 = Wa[(size_t)k1 * M_ + (c - 384)]; }
      wsu[WS_W2P + u] = packh2(v0, v1);
    } else if (i < 401408) {               // WOP: q4 = k4*128 + c
      int u = i - 393216;
      int jm = u & 3, q4 = u >> 2, k4 = q4 >> 7, c = q4 & 127;
      int m0 = k4 * 8 + 2 * jm;
      wsu[WS_WOP + u] = packh2(Wo[(size_t)m0 * I_ + c], Wo[(size_t)(m0 + 1) * I_ + c]);
    } else {                               // WSM: [d][512 k2]
      int u = i - 401408, d = u >> 9, k2 = u & 511;
      int k0 = 2 * k2, k1 = 2 * k2 + 1;
      float v0, v1;
      if (d < 2)      { v0 = Wb[d * H_ + k0];        v1 = Wb[d * H_ + k1]; }
      else if (d < 4) { v0 = Wg[(d - 2) * H_ + k0];  v1 = Wg[(d - 2) * H_ + k1]; }
      else if (d < 6) { v0 = Wgm[(d - 4) * H_ + k0]; v1 = Wgm[(d - 4) * H_ + k1]; }
      else if (d < 9) { v0 = Wsf[k0 * 3 + (d - 6)];  v1 = Wsf[k1 * 3 + (d - 6)]; }
      else            { v0 = Wsf[3 * H_ + k0 * 3 + (d - 9)]; v1 = Wsf[3 * H_ + k1 * 3 + (d - 9)]; }
      wsu[WS_WSM + u] = packh2(v0, v1);
    }
  }
}

// ============ xc precompute: xc[t,b,:] = x[t,b,:] @ Wc_x (fp16) ============
__global__ __launch_bounds__(256)
void ntm_xc(const float* __restrict__ x, const unsigned* __restrict__ wsu,
            unsigned* __restrict__ wsout)
{
  __shared__ __align__(16) _Float16 xt[16 * 128];
  const int tid = threadIdx.x;
  const size_t row0 = (size_t)blockIdx.x * 16;
  for (int i = tid; i < 16 * 128; i += 256)
    xt[i] = (_Float16)x[(row0 + (i >> 7)) * I_ + (i & 127)];
  __syncthreads();
  _Float16* xc16 = (_Float16*)(wsout + WS_XC);
  const uint4* xt4 = (const uint4*)xt;
  const uint4* w4 = (const uint4*)(wsu + WS_WCX);
  for (int cq = 0; cq < 4; ++cq) {
    const int col = cq * 256 + tid;
    float acc[16];
#pragma unroll
    for (int r = 0; r < 16; ++r) acc[r] = 0.f;
#pragma unroll 4
    for (int k4 = 0; k4 < 16; ++k4) {
      uint4 w = w4[k4 * 1024 + col];
#pragma unroll
      for (int r = 0; r < 16; ++r)
        acc[r] = dot4(w, xt4[r * 16 + k4], acc[r]);
    }
#pragma unroll
    for (int r = 0; r < 16; ++r)
      xc16[(row0 + r) * H_ + col] = (_Float16)acc[r];
  }
}

// ============ main: one persistent 1024-thread block per batch element ============
__global__ __launch_bounds__(NT)
void ntm_main(const float* __restrict__ x,
              const float* __restrict__ bc,  const float* __restrict__ bk,
              const float* __restrict__ bbv, const float* __restrict__ bg,
              const float* __restrict__ bsf, const float* __restrict__ bgm,
              const float* __restrict__ be,  const float* __restrict__ ba,
              const float* __restrict__ bo,
              const float* __restrict__ mem0, const float* __restrict__ ww0,
              const float* __restrict__ rw0,  const float* __restrict__ rd0,
              const unsigned* __restrict__ wsu,
              float* __restrict__ out, int useXc)
{
  __shared__ __align__(16) float mem[N_ * MSTR];     // 135168 B
  __shared__ __align__(16) _Float16 ht16[H_];        // 2048
  __shared__ __align__(16) _Float16 rd16[M_];        // 256
  __shared__ __align__(16) _Float16 x16[M_];         // 256 (fallback)
  __shared__ __align__(16) float prevw[2 * N_];      // ww | rw (final, normalized)
  __shared__ __align__(16) float mnv[N_];
  __shared__ __align__(16) float ksh[2 * M_];
  __shared__ __align__(16) float eah[2 * M_];
  __shared__ __align__(16) float wlog[2 * N_];       // raw cosine (no beta)
  __shared__ __align__(16) float wtmp[2 * N_];       // Wo partials (512 used)
  __shared__ __align__(16) float redU[2048];         // [0..1023] rd part | [1024..] sq part
  __shared__ __align__(16) float sdots[24];
  __shared__ __align__(16) float scal[32];
  __shared__ __align__(16) float bcL[H_];
  __shared__ __align__(16) float bkL[256];
  __shared__ __align__(16) float beL[128];
  __shared__ __align__(16) float baL[128];
  __shared__ __align__(16) float boL[128];
  __shared__ __align__(16) float sb[16];

  const int tid = threadIdx.x;
  const int b = blockIdx.x;
  const _Float16* xcg = (const _Float16*)(wsu + WS_XC);
  const uint4* wcx4 = (const uint4*)(wsu + WS_WCX);
  const uint4* wcr4 = (const uint4*)(wsu + WS_WCR);
  const uint4* w2p4 = (const uint4*)(wsu + WS_W2P);
  const uint4* wop4 = (const uint4*)(wsu + WS_WOP);
  const uint4* wsm4 = (const uint4*)(wsu + WS_WSM);
  const uint4* rp4 = (const uint4*)rd16;
  const uint4* hp4 = (const uint4*)ht16;

  // ---------- prologue ----------
  for (int i = tid; i < N_ * M_; i += NT)
    mem[(i >> 7) * MSTR + (i & 127)] = mem0[i];
  bcL[tid] = bc[tid];
  if (tid < 256) bkL[tid] = bk[tid];
  if (tid < 128) { beL[tid] = be[tid]; baL[tid] = ba[tid]; boL[tid] = bo[tid]; }
  if (tid < 12) {
    float v;
    if (tid < 2) v = bbv[tid];
    else if (tid < 4) v = bg[tid - 2];
    else if (tid < 6) v = bgm[tid - 4];
    else v = bsf[tid - 6];
    sb[tid] = v;
  }
  if (tid < 512) wlog[tid] = (tid < 256) ? ww0[tid] : rw0[tid - 256];
  __syncthreads();
  if (tid < 256) {
    float s = 0.f;
#pragma unroll 8
    for (int m = 0; m < M_; ++m) { float v = mem[tid * MSTR + m]; s += v * v; }
    mnv[tid] = fmaxf(sqrtf(s), EPSF);
  }
  {
    int wv = tid >> 6, ln = tid & 63;
    if (wv < 2) {
      float l0 = wlog[wv * N_ + ln], l1 = wlog[wv * N_ + 64 + ln],
            l2 = wlog[wv * N_ + 128 + ln], l3 = wlog[wv * N_ + 192 + ln];
      float mx = wave_rmax(fmaxf(fmaxf(l0, l1), fmaxf(l2, l3)));
      float e0 = __expf(l0 - mx), e1 = __expf(l1 - mx), e2 = __expf(l2 - mx), e3 = __expf(l3 - mx);
      float sm = wave_rsum(e0 + e1 + e2 + e3);
      wlog[wv * N_ + ln] = e0; wlog[wv * N_ + 64 + ln] = e1;
      wlog[wv * N_ + 128 + ln] = e2; wlog[wv * N_ + 192 + ln] = e3;
      if (ln == 0) scal[30 + wv] = 1.f / sm;
    }
  }
  __syncthreads();
  if (tid < 512) prevw[tid] = wlog[tid] * scal[30 + (tid >> 8)];
  if (tid < 64)
    ((unsigned*)rd16)[tid] = packh2(rd0[2 * tid], rd0[2 * tid + 1]);
  if (!useXc && tid >= 64 && tid < 128) {
    int k = tid - 64;
    ((unsigned*)x16)[k] = packh2(x[(size_t)b * I_ + 2 * k], x[(size_t)b * I_ + 2 * k + 1]);
  }
  __syncthreads();

  // ---------- time loop ----------
  for (int t = 0; t < T_; ++t) {
    // S1: phase A (h-col per thread, depth-4 prefetch) + Wo partials (rd(t-1))
    {
      const int j = tid;
      float a0, a1 = 0.f, a2 = 0.f, a3 = 0.f;
      if (useXc) {
        a0 = (float)xcg[((size_t)t * B_ + b) * H_ + j];
      } else {
        a0 = 0.f;
        const uint4* xp4 = (const uint4*)x16;
#pragma unroll 4
        for (int k4 = 0; k4 < 16; k4 += 2) {
          a0 = dot4(wcx4[k4 * 1024 + j], xp4[k4], a0);
          a1 = dot4(wcx4[(k4 + 1) * 1024 + j], xp4[k4 + 1], a1);
        }
      }
      uint4 p0 = wcr4[0 * 1024 + j], p1 = wcr4[1 * 1024 + j],
            p2 = wcr4[2 * 1024 + j], p3 = wcr4[3 * 1024 + j];
      for (int k4 = 0; k4 < 12; k4 += 4) {
        uint4 t0 = p0, t1 = p1, t2 = p2, t3 = p3;
        p0 = wcr4[(k4 + 4) * 1024 + j]; p1 = wcr4[(k4 + 5) * 1024 + j];
        p2 = wcr4[(k4 + 6) * 1024 + j]; p3 = wcr4[(k4 + 7) * 1024 + j];
        a0 = dot4(t0, rp4[k4], a0);     a1 = dot4(t1, rp4[k4 + 1], a1);
        a2 = dot4(t2, rp4[k4 + 2], a2); a3 = dot4(t3, rp4[k4 + 3], a3);
      }
      a0 = dot4(p0, rp4[12], a0); a1 = dot4(p1, rp4[13], a1);
      a2 = dot4(p2, rp4[14], a2); a3 = dot4(p3, rp4[15], a3);
      ht16[j] = (_Float16)tanhf(((a0 + a1) + (a2 + a3)) + bcL[j]);
      if (tid < 512) {               // Wo partials (4 k4-chunks each)
        int c = tid & 127, q = tid >> 7;
        float s = 0.f;
#pragma unroll
        for (int i = 0; i < 4; ++i)
          s = dot4(wop4[(q * 4 + i) * 128 + c], rp4[q * 4 + i], s);
        wtmp[q * 128 + c] = s;
      }
    }
    __syncthreads();

    // S3: phase B, in-wave K-half split: wave w -> cols [w*32,w*32+32),
    //     lane: c = w*32+(l&31), khalf = l>>5; combine via shfl_xor(32).
    //     + sdots (waves 10-15) + out-write(t-1) (tid<128)
    {
      const int w = tid >> 6, l = tid & 63;
      const int c = w * 32 + (l & 31);
      const int kk = (l >> 5) * 64;
      uint4 b0 = w2p4[(size_t)(kk + 0) * 512 + c], b1 = w2p4[(size_t)(kk + 1) * 512 + c],
            b2 = w2p4[(size_t)(kk + 2) * 512 + c], b3 = w2p4[(size_t)(kk + 3) * 512 + c];
      float a0 = 0.f, a1 = 0.f, a2 = 0.f, a3 = 0.f;
      for (int k = 0; k < 60; k += 4) {
        uint4 t0 = b0, t1 = b1, t2 = b2, t3 = b3;
        b0 = w2p4[(size_t)(kk + k + 4) * 512 + c]; b1 = w2p4[(size_t)(kk + k + 5) * 512 + c];
        b2 = w2p4[(size_t)(kk + k + 6) * 512 + c]; b3 = w2p4[(size_t)(kk + k + 7) * 512 + c];
        a0 = dot4(t0, hp4[kk + k], a0);     a1 = dot4(t1, hp4[kk + k + 1], a1);
        a2 = dot4(t2, hp4[kk + k + 2], a2); a3 = dot4(t3, hp4[kk + k + 3], a3);
      }
      a0 = dot4(b0, hp4[kk + 60], a0); a1 = dot4(b1, hp4[kk + 61], a1);
      a2 = dot4(b2, hp4[kk + 62], a2); a3 = dot4(b3, hp4[kk + 63], a3);
      float acc = (a0 + a1) + (a2 + a3);
      acc += __shfl_xor(acc, 32, 64);
      if (l < 32) {
        if (c < 256)      ksh[c] = fmaxf(acc + bkL[c], 0.f);
        else if (c < 384) eah[c - 256] = 1.f / (1.f + __expf(-(acc + beL[c - 256])));
        else              eah[c - 256] = 1.f / (1.f + __expf(-(acc + baL[c - 384])));
      }
      if (w >= 10) {                 // 24 half-dots, 4 per wave
#pragma unroll
        for (int i = 0; i < 4; ++i) {
          int hd = (w - 10) * 4 + i;
          int d = hd >> 1, half = hd & 1;
          float s = dot4(wsm4[d * 128 + half * 64 + l], hp4[half * 64 + l], 0.f);
          s = wave_rsum(s);
          if (l == 0) sdots[hd] = s;
        }
      }
      if (tid < 128 && t > 0) {
        float o = boL[tid] + wtmp[tid] + wtmp[128 + tid] + wtmp[256 + tid] + wtmp[384 + tid];
        out[((size_t)(t - 1) * B_ + b) * I_ + tid] = o;
      }
    }
    __syncthreads();

    // S6: cosine, all 16 waves: (h = wv&1, rows nblk*32+(ln&31), M-half = ln>>5),
    //     key-norm computed inline from the same k registers.
    {
      int wv = tid >> 6, ln = tid & 63;
      int h = wv & 1, nblk = wv >> 1;
      int r = nblk * 32 + (ln & 31), mh = ln >> 5;
      const float4* kp = (const float4*)&ksh[h * 128 + mh * 64];
      const float* mrow = &mem[r * MSTR + mh * 64];
      float dot = 0.f, kq = 0.f;
#pragma unroll
      for (int i = 0; i < 16; ++i) {
        float4 kv = kp[i];
        float4 mv = *(const float4*)&mrow[i * 4];
        dot += kv.x * mv.x + kv.y * mv.y + kv.z * mv.z + kv.w * mv.w;
        kq  += kv.x * kv.x + kv.y * kv.y + kv.z * kv.z + kv.w * kv.w;
      }
      dot += __shfl_xor(dot, 32, 64);
      kq  += __shfl_xor(kq, 32, 64);
      if (ln < 32) {
        float kn = fmaxf(sqrtf(kq), EPSF);
        wlog[h * N_ + r] = dot / (kn * mnv[r]);
      }
    }
    __syncthreads();

    // S7: addressing chain, 2 waves (one per head), all in registers.
    if (tid < 128) {
      int h = tid >> 6, ln = tid & 63;
      // scalars, redundantly per lane
      float Sb = sdots[2 * h] + sdots[2 * h + 1] + sb[h];
      float beta = (Sb > 20.f) ? Sb : log1pf(__expf(Sb));
      float g = 1.f / (1.f + __expf(-(sdots[2 * (2 + h)] + sdots[2 * (2 + h) + 1] + sb[2 + h])));
      float gam = fmaxf(sdots[2 * (4 + h)] + sdots[2 * (4 + h) + 1] + sb[4 + h], 0.f) + 1.f;
      float t0 = sdots[2 * (6 + 3 * h)] + sdots[2 * (6 + 3 * h) + 1] + sb[6 + 3 * h];
      float t1 = sdots[2 * (7 + 3 * h)] + sdots[2 * (7 + 3 * h) + 1] + sb[7 + 3 * h];
      float t2 = sdots[2 * (8 + 3 * h)] + sdots[2 * (8 + 3 * h) + 1] + sb[8 + 3 * h];
      float mx3 = fmaxf(t0, fmaxf(t1, t2));
      float e0s = __expf(t0 - mx3), e1s = __expf(t1 - mx3), e2s = __expf(t2 - mx3);
      float inv3 = 1.f / (e0s + e1s + e2s);
      float s0 = e0s * inv3, s1 = e1s * inv3, s2 = e2s * inv3;
      // softmax(beta*cos)
      float w0 = beta * wlog[h * N_ + ln],        w1 = beta * wlog[h * N_ + 64 + ln];
      float w2 = beta * wlog[h * N_ + 128 + ln],  w3 = beta * wlog[h * N_ + 192 + ln];
      float mx = wave_rmax(fmaxf(fmaxf(w0, w1), fmaxf(w2, w3)));
      w0 = __expf(w0 - mx); w1 = __expf(w1 - mx); w2 = __expf(w2 - mx); w3 = __expf(w3 - mx);
      float inv = 1.f / wave_rsum(w0 + w1 + w2 + w3);
      // interpolate
      w0 = g * w0 * inv + (1.f - g) * prevw[h * N_ + ln];
      w1 = g * w1 * inv + (1.f - g) * prevw[h * N_ + 64 + ln];
      w2 = g * w2 * inv + (1.f - g) * prevw[h * N_ + 128 + ln];
      w3 = g * w3 * inv + (1.f - g) * prevw[h * N_ + 192 + ln];
      // circular shift: left = w[n-1], right = w[n+1]
      int lm = (ln + 63) & 63, lp = (ln + 1) & 63;
      float l0 = __shfl(w0, lm, 64), l1 = __shfl(w1, lm, 64),
            l2 = __shfl(w2, lm, 64), l3 = __shfl(w3, lm, 64);
      float e0 = __shfl(w0, 63, 64), e1 = __shfl(w1, 63, 64),
            e2 = __shfl(w2, 63, 64), e3 = __shfl(w3, 63, 64);
      if (ln == 0) { l0 = e3; l1 = e0; l2 = e1; l3 = e2; }
      float r0 = __shfl(w0, lp, 64), r1 = __shfl(w1, lp, 64),
            r2 = __shfl(w2, lp, 64), r3 = __shfl(w3, lp, 64);
      float f0 = __shfl(w0, 0, 64), f1 = __shfl(w1, 0, 64),
            f2 = __shfl(w2, 0, 64), f3 = __shfl(w3, 0, 64);
      if (ln == 63) { r0 = f1; r1 = f2; r2 = f3; r3 = f0; }
      float u0 = s0 * l0 + s1 * w0 + s2 * r0;
      float u1 = s0 * l1 + s1 * w1 + s2 * r1;
      float u2 = s0 * l2 + s1 * w2 + s2 * r2;
      float u3 = s0 * l3 + s1 * w3 + s2 * r3;
      // sharpen + normalize
      u0 = __powf(u0, gam); u1 = __powf(u1, gam);
      u2 = __powf(u2, gam); u3 = __powf(u3, gam);
      float invs = 1.f / wave_rsum(u0 + u1 + u2 + u3);
      prevw[h * N_ + ln] = u0 * invs;
      prevw[h * N_ + 64 + ln] = u1 * invs;
      prevw[h * N_ + 128 + ln] = u2 * invs;
      prevw[h * N_ + 192 + ln] = u3 * invs;
    }
    __syncthreads();

    // S11: memory update (thread = (row, M-quarter)) + sq partials
    {
      int n = tid & 255, q = tid >> 8;
      float wwn = prevw[n];
      float* mrow = &mem[n * MSTR + q * 32];
      const float4* ep = (const float4*)&eah[q * 32];
      const float4* ap = (const float4*)&eah[128 + q * 32];
      float sq = 0.f;
#pragma unroll
      for (int i = 0; i < 8; ++i) {
        float4 mv = *(float4*)&mrow[i * 4];
        float4 ev = ep[i], av = ap[i];
        mv.x = mv.x * (1.f - wwn * ev.x) + wwn * av.x;
        mv.y = mv.y * (1.f - wwn * ev.y) + wwn * av.y;
        mv.z = mv.z * (1.f - wwn * ev.z) + wwn * av.z;
        mv.w = mv.w * (1.f - wwn * ev.w) + wwn * av.w;
        sq += mv.x * mv.x + mv.y * mv.y + mv.z * mv.z + mv.w * mv.w;
        *(float4*)&mrow[i * 4] = mv;
      }
      redU[1024 + q * 256 + n] = sq;
    }
    __syncthreads();

    // S12: rd partials vectorized over m (tid<256) | mnv finalize (512-767)
    if (tid < 256) {
      int m4 = tid & 31, g = tid >> 5;       // 8 groups of 32 rows
      const float* base = &mem[(g * 32) * MSTR + m4 * 4];
      float4 acc = {0.f, 0.f, 0.f, 0.f};
#pragma unroll 8
      for (int i = 0; i < 32; ++i) {
        float rw = prevw[256 + g * 32 + i];
        float4 mv = *(const float4*)&base[i * MSTR];
        acc.x += rw * mv.x; acc.y += rw * mv.y; acc.z += rw * mv.z; acc.w += rw * mv.w;
      }
      *(float4*)&redU[g * 128 + m4 * 4] = acc;
    } else if (tid >= 512 && tid < 768) {
      int n = tid - 512;
      float s = redU[1024 + n] + redU[1280 + n] + redU[1536 + n] + redU[1792 + n];
      mnv[n] = fmaxf(sqrtf(s), EPSF);
    }
    __syncthreads();

    // S13: rd finalize + pack | next-x pack (fallback)
    {
      if (tid < 64) {
        float r0 = 0.f, r1 = 0.f;
#pragma unroll
        for (int g = 0; g < 8; ++g) {
          r0 += redU[g * 128 + 2 * tid];
          r1 += redU[g * 128 + 2 * tid + 1];
        }
        ((unsigned*)rd16)[tid] = packh2(r0, r1);
      } else if (!useXc && tid >= 768 && tid < 832 && t < T_ - 1) {
        int k = tid - 768;
        const float* xr = &x[((size_t)(t + 1) * B_ + b) * I_];
        ((unsigned*)x16)[k] = packh2(xr[2 * k], xr[2 * k + 1]);
      }
    }
    __syncthreads();
  }

  // ---------- epilogue: Wo for t = T-1 ----------
  if (tid < 512) {
    int c = tid & 127, q = tid >> 7;
    float s = 0.f;
#pragma unroll
    for (int i = 0; i < 4; ++i)
      s = dot4(wop4[(q * 4 + i) * 128 + c], rp4[q * 4 + i], s);
    wtmp[q * 128 + c] = s;
  }
  __syncthreads();
  if (tid < 128) {
    float o = boL[tid] + wtmp[tid] + wtmp[128 + tid] + wtmp[256 + tid] + wtmp[384 + tid];
    out[((size_t)(T_ - 1) * B_ + b) * I_ + tid] = o;
  }
}

extern "C" void kernel_launch(void* const* d_in, const int* in_sizes, int n_in,
                              void* d_out, int out_size, void* d_ws, size_t ws_size,
                              hipStream_t stream) {
  (void)in_sizes; (void)n_in; (void)out_size;

  const float* x    = (const float*)d_in[0];
  const float* Wc   = (const float*)d_in[1];
  const float* bc   = (const float*)d_in[2];
  const float* Wk   = (const float*)d_in[3];
  const float* bk   = (const float*)d_in[4];
  const float* Wb   = (const float*)d_in[5];
  const float* bbv  = (const float*)d_in[6];
  const float* Wg   = (const float*)d_in[7];
  const float* bg   = (const float*)d_in[8];
  const float* Wsf  = (const float*)d_in[9];
  const float* bsf  = (const float*)d_in[10];
  const float* Wgm  = (const float*)d_in[11];
  const float* bgm  = (const float*)d_in[12];
  const float* We   = (const float*)d_in[13];
  const float* be   = (const float*)d_in[14];
  const float* Wa   = (const float*)d_in[15];
  const float* ba   = (const float*)d_in[16];
  const float* Wo   = (const float*)d_in[17];
  const float* bo   = (const float*)d_in[18];
  const float* mem0 = (const float*)d_in[19];
  const float* ww0  = (const float*)d_in[20];
  const float* rw0  = (const float*)d_in[21];
  const float* rd0  = (const float*)d_in[22];
  float* out = (float*)d_out;
  unsigned* wsu = (unsigned*)d_ws;

  const int useXc = (ws_size >= WS_BYTES_NEEDED) ? 1 : 0;

  ntm_pack<<<dim3(512), dim3(256), 0, stream>>>(Wc, Wk, Wb, Wg, Wsf, Wgm, We, Wa, Wo, wsu);
  if (useXc)
    ntm_xc<<<dim3(T_ * B_ / 16), dim3(256), 0, stream>>>(x, wsu, wsu);
  ntm_main<<<dim3(NB), dim3(NT), 0, stream>>>(x, bc, bk, bbv, bg, bsf, bgm, be, ba, bo,
                                              mem0, ww0, rw0, rd0, wsu, out, useXc);
}

// Round 6
// 2402.982 us; speedup vs baseline: 1.9130x; 1.9130x over previous
//
#include <hip/hip_runtime.h>
#include <math.h>

#define T_ 64
#define B_ 256
#define N_ 256
#define M_ 128
#define H_ 1024
#define I_ 128
#define NB 256
#define NT 1024
#define MSTR 132          // mem row stride (floats)
#define EPSF 1e-8f

// ---- ws layout (uint offsets). Big weights THREAD-MAJOR [k-chunk][col]:
// consecutive lanes read consecutive 16B -> coalesced wave transactions. ----
#define WS_WCX 0                 // [16 k4][1024 h] uint4  (Wc x-part)
#define WS_WCR 65536             // [16 k4][1024 h] uint4  (Wc rd-part)
#define WS_W2P 131072            // [128 k4][512 c] uint4  (Wk0|Wk1|We|Wa)
#define WS_WOP 393216            // [16 k4][128 c]  uint4  (Wo)
#define WS_WSM 401408            // [12 d][512 k2]  uint   (beta,g,gamma,shift)
#define WS_XC  407552            // _Float16 xc[T*B][H] (32 MB)
#define WS_BYTES_NEEDED ((size_t)(407552 + 8388608) * 4)

typedef _Float16 h2_t __attribute__((ext_vector_type(2)));

__device__ __forceinline__ float fdot2(unsigned a, unsigned b, float c) {
  union { unsigned u; h2_t h; } ua, ub;
  ua.u = a; ub.u = b;
  return __builtin_amdgcn_fdot2(ua.h, ub.h, c, false);
}
__device__ __forceinline__ unsigned packh2(float a, float b) {
  union { h2_t h; unsigned u; } v;
  v.h = h2_t{(_Float16)a, (_Float16)b};
  return v.u;
}
__device__ __forceinline__ float dot4(uint4 w, uint4 h, float acc) {
  acc = fdot2(w.x, h.x, acc); acc = fdot2(w.y, h.y, acc);
  acc = fdot2(w.z, h.z, acc); acc = fdot2(w.w, h.w, acc);
  return acc;
}
__device__ __forceinline__ float wave_rsum(float v) {
#pragma unroll
  for (int o = 32; o > 0; o >>= 1) v += __shfl_xor(v, o, 64);
  return v;
}
__device__ __forceinline__ float wave_rmax(float v) {
#pragma unroll
  for (int o = 32; o > 0; o >>= 1) v = fmaxf(v, __shfl_xor(v, o, 64));
  return v;
}

// ============ pack: fp32 -> fp16, thread-major chunked layouts ============
__global__ void ntm_pack(const float* __restrict__ Wc, const float* __restrict__ Wk,
                         const float* __restrict__ Wb, const float* __restrict__ Wg,
                         const float* __restrict__ Wsf, const float* __restrict__ Wgm,
                         const float* __restrict__ We, const float* __restrict__ Wa,
                         const float* __restrict__ Wo,
                         unsigned* __restrict__ wsu)
{
  const int total = 407552;
  for (int i = blockIdx.x * blockDim.x + threadIdx.x; i < total;
       i += gridDim.x * blockDim.x) {
    if (i < 65536) {                       // WCX: q4 = k4*1024 + h
      int jm = i & 3, q4 = i >> 2, k4 = q4 >> 10, h = q4 & 1023;
      int k0 = k4 * 8 + 2 * jm;
      wsu[WS_WCX + i] = packh2(Wc[(size_t)k0 * H_ + h], Wc[(size_t)(k0 + 1) * H_ + h]);
    } else if (i < 131072) {               // WCR: rd-part rows 128..255
      int u = i - 65536;
      int jm = u & 3, q4 = u >> 2, k4 = q4 >> 10, h = q4 & 1023;
      int k0 = 128 + k4 * 8 + 2 * jm;
      wsu[WS_WCR + u] = packh2(Wc[(size_t)k0 * H_ + h], Wc[(size_t)(k0 + 1) * H_ + h]);
    } else if (i < 393216) {               // W2P: q4 = k4*512 + c
      int u = i - 131072;
      int jm = u & 3, q4 = u >> 2, k4 = q4 >> 9, c = q4 & 511;
      int k0 = k4 * 8 + 2 * jm, k1 = k0 + 1;
      float v0, v1;
      if (c < 128)      { v0 = Wk[(size_t)k0 * M_ + c];           v1 = Wk[(size_t)k1 * M_ + c]; }
      else if (c < 256) { v0 = Wk[(size_t)H_ * M_ + (size_t)k0 * M_ + (c - 128)];
                          v1 = Wk[(size_t)H_ * M_ + (size_t)k1 * M_ + (c - 128)]; }
      else if (c < 384) { v0 = We[(size_t)k0 * M_ + (c - 256)];   v1 = We[(size_t)k1 * M_ + (c - 256)]; }
      else              { v0 = Wa[(size_t)k0 * M_ + (c - 384)];   v1 = Wa[(size_t)k1 * M_ + (c - 384)]; }
      wsu[WS_W2P + u] = packh2(v0, v1);
    } else if (i < 401408) {               // WOP: q4 = k4*128 + c
      int u = i - 393216;
      int jm = u & 3, q4 = u >> 2, k4 = q4 >> 7, c = q4 & 127;
      int m0 = k4 * 8 + 2 * jm;
      wsu[WS_WOP + u] = packh2(Wo[(size_t)m0 * I_ + c], Wo[(size_t)(m0 + 1) * I_ + c]);
    } else {                               // WSM: [12 d][512 k2]
      int u = i - 401408, d = u >> 9, k2 = u & 511;
      int k0 = 2 * k2, k1 = 2 * k2 + 1;
      float v0, v1;
      if (d < 2)      { v0 = Wb[d * H_ + k0];        v1 = Wb[d * H_ + k1]; }
      else if (d < 4) { v0 = Wg[(d - 2) * H_ + k0];  v1 = Wg[(d - 2) * H_ + k1]; }
      else if (d < 6) { v0 = Wgm[(d - 4) * H_ + k0]; v1 = Wgm[(d - 4) * H_ + k1]; }
      else if (d < 9) { v0 = Wsf[k0 * 3 + (d - 6)];  v1 = Wsf[k1 * 3 + (d - 6)]; }
      else            { v0 = Wsf[3 * H_ + k0 * 3 + (d - 9)]; v1 = Wsf[3 * H_ + k1 * 3 + (d - 9)]; }
      wsu[WS_WSM + u] = packh2(v0, v1);
    }
  }
}

// ============ xc precompute: xc[t,b,:] = x[t,b,:] @ Wc_x (fp16) ============
__global__ __launch_bounds__(256)
void ntm_xc(const float* __restrict__ x, const unsigned* __restrict__ wsu,
            unsigned* __restrict__ wsout)
{
  __shared__ __align__(16) _Float16 xt[16 * 128];
  const int tid = threadIdx.x;
  const size_t row0 = (size_t)blockIdx.x * 16;
  for (int i = tid; i < 16 * 128; i += 256)
    xt[i] = (_Float16)x[(row0 + (i >> 7)) * I_ + (i & 127)];
  __syncthreads();
  _Float16* xc16 = (_Float16*)(wsout + WS_XC);
  const uint4* xt4 = (const uint4*)xt;
  const uint4* w4 = (const uint4*)(wsu + WS_WCX);
  for (int cq = 0; cq < 4; ++cq) {
    const int col = cq * 256 + tid;
    float acc[16];
#pragma unroll
    for (int r = 0; r < 16; ++r) acc[r] = 0.f;
#pragma unroll 4
    for (int k4 = 0; k4 < 16; ++k4) {
      uint4 w = w4[k4 * 1024 + col];
#pragma unroll
      for (int r = 0; r < 16; ++r)
        acc[r] = dot4(w, xt4[r * 16 + k4], acc[r]);
    }
#pragma unroll
    for (int r = 0; r < 16; ++r)
      xc16[(row0 + r) * H_ + col] = (_Float16)acc[r];
  }
}

// ============ main: one persistent 1024-thread block per batch element ============
// __launch_bounds__(1024, 4): 4 waves/EU (= the single LDS-resident block) ->
// VGPR cap 128 instead of 64. R5 spilled at the default cap (FETCH 2.7 GB of
// scratch traffic); this is the fix.
__global__ __launch_bounds__(NT, 4)
void ntm_main(const float* __restrict__ x,
              const float* __restrict__ bc,  const float* __restrict__ bk,
              const float* __restrict__ bbv, const float* __restrict__ bg,
              const float* __restrict__ bsf, const float* __restrict__ bgm,
              const float* __restrict__ be,  const float* __restrict__ ba,
              const float* __restrict__ bo,
              const float* __restrict__ mem0, const float* __restrict__ ww0,
              const float* __restrict__ rw0,  const float* __restrict__ rd0,
              const unsigned* __restrict__ wsu,
              float* __restrict__ out, int useXc)
{
  __shared__ __align__(16) float mem[N_ * MSTR];     // 135168 B
  __shared__ __align__(16) _Float16 ht16[H_];        // 2048
  __shared__ __align__(16) _Float16 rd16[M_];        // 256
  __shared__ __align__(16) _Float16 x16[M_];         // 256 (fallback)
  __shared__ __align__(16) float prevw[2 * N_];      // ww | rw (final, normalized)
  __shared__ __align__(16) float mnv[N_];
  __shared__ __align__(16) float ksh[2 * M_];
  __shared__ __align__(16) float eah[2 * M_];
  __shared__ __align__(16) float wlog[2 * N_];       // raw cosine (no beta)
  __shared__ __align__(16) float wtmp[2 * N_];       // Wo partials (512 used)
  __shared__ __align__(16) float redU[2048];         // rd part | sq part
  __shared__ __align__(16) float sdots[24];
  __shared__ __align__(16) float scal[32];
  __shared__ __align__(16) float bcL[H_];
  __shared__ __align__(16) float bkL[256];
  __shared__ __align__(16) float beL[128];
  __shared__ __align__(16) float baL[128];
  __shared__ __align__(16) float boL[128];
  __shared__ __align__(16) float sb[16];

  const int tid = threadIdx.x;
  const int b = blockIdx.x;
  const _Float16* xcg = (const _Float16*)(wsu + WS_XC);
  const uint4* wcx4 = (const uint4*)(wsu + WS_WCX);
  const uint4* wcr4 = (const uint4*)(wsu + WS_WCR);
  const uint4* w2p4 = (const uint4*)(wsu + WS_W2P);
  const uint4* wop4 = (const uint4*)(wsu + WS_WOP);
  const uint4* wsm4 = (const uint4*)(wsu + WS_WSM);
  const uint4* rp4 = (const uint4*)rd16;
  const uint4* hp4 = (const uint4*)ht16;

  // ---------- prologue ----------
  for (int i = tid; i < N_ * M_; i += NT)
    mem[(i >> 7) * MSTR + (i & 127)] = mem0[i];
  bcL[tid] = bc[tid];
  if (tid < 256) bkL[tid] = bk[tid];
  if (tid < 128) { beL[tid] = be[tid]; baL[tid] = ba[tid]; boL[tid] = bo[tid]; }
  if (tid < 12) {
    float v;
    if (tid < 2) v = bbv[tid];
    else if (tid < 4) v = bg[tid - 2];
    else if (tid < 6) v = bgm[tid - 4];
    else v = bsf[tid - 6];
    sb[tid] = v;
  }
  if (tid < 512) wlog[tid] = (tid < 256) ? ww0[tid] : rw0[tid - 256];
  __syncthreads();
  if (tid < 256) {
    float s = 0.f;
#pragma unroll 8
    for (int m = 0; m < M_; ++m) { float v = mem[tid * MSTR + m]; s += v * v; }
    mnv[tid] = fmaxf(sqrtf(s), EPSF);
  }
  {
    int wv = tid >> 6, ln = tid & 63;
    if (wv < 2) {
      float l0 = wlog[wv * N_ + ln], l1 = wlog[wv * N_ + 64 + ln],
            l2 = wlog[wv * N_ + 128 + ln], l3 = wlog[wv * N_ + 192 + ln];
      float mx = wave_rmax(fmaxf(fmaxf(l0, l1), fmaxf(l2, l3)));
      float e0 = __expf(l0 - mx), e1 = __expf(l1 - mx), e2 = __expf(l2 - mx), e3 = __expf(l3 - mx);
      float sm = wave_rsum(e0 + e1 + e2 + e3);
      wlog[wv * N_ + ln] = e0; wlog[wv * N_ + 64 + ln] = e1;
      wlog[wv * N_ + 128 + ln] = e2; wlog[wv * N_ + 192 + ln] = e3;
      if (ln == 0) scal[30 + wv] = 1.f / sm;
    }
  }
  __syncthreads();
  if (tid < 512) prevw[tid] = wlog[tid] * scal[30 + (tid >> 8)];
  if (tid < 64)
    ((unsigned*)rd16)[tid] = packh2(rd0[2 * tid], rd0[2 * tid + 1]);
  if (!useXc && tid >= 64 && tid < 128) {
    int k = tid - 64;
    ((unsigned*)x16)[k] = packh2(x[(size_t)b * I_ + 2 * k], x[(size_t)b * I_ + 2 * k + 1]);
  }
  __syncthreads();

  // ---------- time loop ----------
  for (int t = 0; t < T_; ++t) {
    // S1: phase A (h-col per thread, compiler-scheduled loads, 4 accumulators)
    //     + fused Wo partials of rd(t-1) on tid<512
    {
      const int j = tid;
      float a0, a1 = 0.f, a2 = 0.f, a3 = 0.f;
      if (useXc) {
        a0 = (float)xcg[((size_t)t * B_ + b) * H_ + j];
      } else {
        a0 = 0.f;
        const uint4* xp4 = (const uint4*)x16;
#pragma unroll
        for (int k4 = 0; k4 < 16; k4 += 4) {
          a0 = dot4(wcx4[k4 * 1024 + j], xp4[k4], a0);
          a1 = dot4(wcx4[(k4 + 1) * 1024 + j], xp4[k4 + 1], a1);
          a2 = dot4(wcx4[(k4 + 2) * 1024 + j], xp4[k4 + 2], a2);
          a3 = dot4(wcx4[(k4 + 3) * 1024 + j], xp4[k4 + 3], a3);
        }
      }
#pragma unroll
      for (int k4 = 0; k4 < 16; k4 += 4) {
        a0 = dot4(wcr4[k4 * 1024 + j], rp4[k4], a0);
        a1 = dot4(wcr4[(k4 + 1) * 1024 + j], rp4[k4 + 1], a1);
        a2 = dot4(wcr4[(k4 + 2) * 1024 + j], rp4[k4 + 2], a2);
        a3 = dot4(wcr4[(k4 + 3) * 1024 + j], rp4[k4 + 3], a3);
      }
      ht16[j] = (_Float16)tanhf(((a0 + a1) + (a2 + a3)) + bcL[j]);
      if (tid < 512) {               // Wo partials (4 k4-chunks each)
        int c = tid & 127, q = tid >> 7;
        float s = 0.f;
#pragma unroll
        for (int i = 0; i < 4; ++i)
          s = dot4(wop4[(q * 4 + i) * 128 + c], rp4[q * 4 + i], s);
        wtmp[q * 128 + c] = s;
      }
    }
    __syncthreads();

    // S3: phase B, in-wave K-half split: wave w -> cols [w*32,w*32+32),
    //     lane: c = w*32+(l&31), khalf = l>>5; combine via shfl_xor(32).
    //     + sdots (waves 10-15) + out-write(t-1) (tid<128)
    {
      const int w = tid >> 6, l = tid & 63;
      const int c = w * 32 + (l & 31);
      const int kk = (l >> 5) * 64;
      float a0 = 0.f, a1 = 0.f, a2 = 0.f, a3 = 0.f;
#pragma unroll 4
      for (int k = 0; k < 64; k += 4) {
        a0 = dot4(w2p4[(size_t)(kk + k) * 512 + c],     hp4[kk + k],     a0);
        a1 = dot4(w2p4[(size_t)(kk + k + 1) * 512 + c], hp4[kk + k + 1], a1);
        a2 = dot4(w2p4[(size_t)(kk + k + 2) * 512 + c], hp4[kk + k + 2], a2);
        a3 = dot4(w2p4[(size_t)(kk + k + 3) * 512 + c], hp4[kk + k + 3], a3);
      }
      float acc = (a0 + a1) + (a2 + a3);
      acc += __shfl_xor(acc, 32, 64);
      if (l < 32) {
        if (c < 256)      ksh[c] = fmaxf(acc + bkL[c], 0.f);
        else if (c < 384) eah[c - 256] = 1.f / (1.f + __expf(-(acc + beL[c - 256])));
        else              eah[c - 256] = 1.f / (1.f + __expf(-(acc + baL[c - 384])));
      }
      if (w >= 10) {                 // 24 half-dots, 4 per wave
#pragma unroll
        for (int i = 0; i < 4; ++i) {
          int hd = (w - 10) * 4 + i;
          int d = hd >> 1, half = hd & 1;
          float s = dot4(wsm4[d * 128 + half * 64 + l], hp4[half * 64 + l], 0.f);
          s = wave_rsum(s);
          if (l == 0) sdots[hd] = s;
        }
      }
      if (tid < 128 && t > 0) {
        float o = boL[tid] + wtmp[tid] + wtmp[128 + tid] + wtmp[256 + tid] + wtmp[384 + tid];
        out[((size_t)(t - 1) * B_ + b) * I_ + tid] = o;
      }
    }
    __syncthreads();

    // S6: cosine, all 16 waves: (h = wv&1, rows nblk*32+(ln&31), M-half = ln>>5),
    //     key-norm computed inline from the same k registers.
    {
      int wv = tid >> 6, ln = tid & 63;
      int h = wv & 1, nblk = wv >> 1;
      int r = nblk * 32 + (ln & 31), mh = ln >> 5;
      const float4* kp = (const float4*)&ksh[h * 128 + mh * 64];
      const float* mrow = &mem[r * MSTR + mh * 64];
      float dot = 0.f, kq = 0.f;
#pragma unroll
      for (int i = 0; i < 16; ++i) {
        float4 kv = kp[i];
        float4 mv = *(const float4*)&mrow[i * 4];
        dot += kv.x * mv.x + kv.y * mv.y + kv.z * mv.z + kv.w * mv.w;
        kq  += kv.x * kv.x + kv.y * kv.y + kv.z * kv.z + kv.w * kv.w;
      }
      dot += __shfl_xor(dot, 32, 64);
      kq  += __shfl_xor(kq, 32, 64);
      if (ln < 32) {
        float kn = fmaxf(sqrtf(kq), EPSF);
        wlog[h * N_ + r] = dot / (kn * mnv[r]);
      }
    }
    __syncthreads();

    // S7: addressing chain, 2 waves (one per head), all in registers.
    if (tid < 128) {
      int h = tid >> 6, ln = tid & 63;
      float Sb = sdots[2 * h] + sdots[2 * h + 1] + sb[h];
      float beta = (Sb > 20.f) ? Sb : log1pf(__expf(Sb));
      float g = 1.f / (1.f + __expf(-(sdots[2 * (2 + h)] + sdots[2 * (2 + h) + 1] + sb[2 + h])));
      float gam = fmaxf(sdots[2 * (4 + h)] + sdots[2 * (4 + h) + 1] + sb[4 + h], 0.f) + 1.f;
      float t0 = sdots[2 * (6 + 3 * h)] + sdots[2 * (6 + 3 * h) + 1] + sb[6 + 3 * h];
      float t1 = sdots[2 * (7 + 3 * h)] + sdots[2 * (7 + 3 * h) + 1] + sb[7 + 3 * h];
      float t2 = sdots[2 * (8 + 3 * h)] + sdots[2 * (8 + 3 * h) + 1] + sb[8 + 3 * h];
      float mx3 = fmaxf(t0, fmaxf(t1, t2));
      float e0s = __expf(t0 - mx3), e1s = __expf(t1 - mx3), e2s = __expf(t2 - mx3);
      float inv3 = 1.f / (e0s + e1s + e2s);
      float s0 = e0s * inv3, s1 = e1s * inv3, s2 = e2s * inv3;
      // softmax(beta*cos)
      float w0 = beta * wlog[h * N_ + ln],        w1 = beta * wlog[h * N_ + 64 + ln];
      float w2 = beta * wlog[h * N_ + 128 + ln],  w3 = beta * wlog[h * N_ + 192 + ln];
      float mx = wave_rmax(fmaxf(fmaxf(w0, w1), fmaxf(w2, w3)));
      w0 = __expf(w0 - mx); w1 = __expf(w1 - mx); w2 = __expf(w2 - mx); w3 = __expf(w3 - mx);
      float inv = 1.f / wave_rsum(w0 + w1 + w2 + w3);
      // interpolate
      w0 = g * w0 * inv + (1.f - g) * prevw[h * N_ + ln];
      w1 = g * w1 * inv + (1.f - g) * prevw[h * N_ + 64 + ln];
      w2 = g * w2 * inv + (1.f - g) * prevw[h * N_ + 128 + ln];
      w3 = g * w3 * inv + (1.f - g) * prevw[h * N_ + 192 + ln];
      // circular shift: left = w[n-1], right = w[n+1]
      int lm = (ln + 63) & 63, lp = (ln + 1) & 63;
      float l0 = __shfl(w0, lm, 64), l1 = __shfl(w1, lm, 64),
            l2 = __shfl(w2, lm, 64), l3 = __shfl(w3, lm, 64);
      float e0 = __shfl(w0, 63, 64), e1 = __shfl(w1, 63, 64),
            e2 = __shfl(w2, 63, 64), e3 = __shfl(w3, 63, 64);
      if (ln == 0) { l0 = e3; l1 = e0; l2 = e1; l3 = e2; }
      float r0 = __shfl(w0, lp, 64), r1 = __shfl(w1, lp, 64),
            r2 = __shfl(w2, lp, 64), r3 = __shfl(w3, lp, 64);
      float f0 = __shfl(w0, 0, 64), f1 = __shfl(w1, 0, 64),
            f2 = __shfl(w2, 0, 64), f3 = __shfl(w3, 0, 64);
      if (ln == 63) { r0 = f1; r1 = f2; r2 = f3; r3 = f0; }
      float u0 = s0 * l0 + s1 * w0 + s2 * r0;
      float u1 = s0 * l1 + s1 * w1 + s2 * r1;
      float u2 = s0 * l2 + s1 * w2 + s2 * r2;
      float u3 = s0 * l3 + s1 * w3 + s2 * r3;
      // sharpen + normalize
      u0 = __powf(u0, gam); u1 = __powf(u1, gam);
      u2 = __powf(u2, gam); u3 = __powf(u3, gam);
      float invs = 1.f / wave_rsum(u0 + u1 + u2 + u3);
      prevw[h * N_ + ln] = u0 * invs;
      prevw[h * N_ + 64 + ln] = u1 * invs;
      prevw[h * N_ + 128 + ln] = u2 * invs;
      prevw[h * N_ + 192 + ln] = u3 * invs;
    }
    __syncthreads();

    // S11: memory update (thread = (row, M-quarter)) + sq partials
    {
      int n = tid & 255, q = tid >> 8;
      float wwn = prevw[n];
      float* mrow = &mem[n * MSTR + q * 32];
      const float4* ep = (const float4*)&eah[q * 32];
      const float4* ap = (const float4*)&eah[128 + q * 32];
      float sq = 0.f;
#pragma unroll
      for (int i = 0; i < 8; ++i) {
        float4 mv = *(float4*)&mrow[i * 4];
        float4 ev = ep[i], av = ap[i];
        mv.x = mv.x * (1.f - wwn * ev.x) + wwn * av.x;
        mv.y = mv.y * (1.f - wwn * ev.y) + wwn * av.y;
        mv.z = mv.z * (1.f - wwn * ev.z) + wwn * av.z;
        mv.w = mv.w * (1.f - wwn * ev.w) + wwn * av.w;
        sq += mv.x * mv.x + mv.y * mv.y + mv.z * mv.z + mv.w * mv.w;
        *(float4*)&mrow[i * 4] = mv;
      }
      redU[1024 + q * 256 + n] = sq;
    }
    __syncthreads();

    // S12: rd partials vectorized over m (tid<256) | mnv finalize (512-767)
    if (tid < 256) {
      int m4 = tid & 31, g = tid >> 5;       // 8 groups of 32 rows
      const float* base = &mem[(g * 32) * MSTR + m4 * 4];
      float4 acc = {0.f, 0.f, 0.f, 0.f};
#pragma unroll 8
      for (int i = 0; i < 32; ++i) {
        float rw = prevw[256 + g * 32 + i];
        float4 mv = *(const float4*)&base[i * MSTR];
        acc.x += rw * mv.x; acc.y += rw * mv.y; acc.z += rw * mv.z; acc.w += rw * mv.w;
      }
      *(float4*)&redU[g * 128 + m4 * 4] = acc;
    } else if (tid >= 512 && tid < 768) {
      int n = tid - 512;
      float s = redU[1024 + n] + redU[1280 + n] + redU[1536 + n] + redU[1792 + n];
      mnv[n] = fmaxf(sqrtf(s), EPSF);
    }
    __syncthreads();

    // S13: rd finalize + pack | next-x pack (fallback)
    {
      if (tid < 64) {
        float r0 = 0.f, r1 = 0.f;
#pragma unroll
        for (int g = 0; g < 8; ++g) {
          r0 += redU[g * 128 + 2 * tid];
          r1 += redU[g * 128 + 2 * tid + 1];
        }
        ((unsigned*)rd16)[tid] = packh2(r0, r1);
      } else if (!useXc && tid >= 768 && tid < 832 && t < T_ - 1) {
        int k = tid - 768;
        const float* xr = &x[((size_t)(t + 1) * B_ + b) * I_];
        ((unsigned*)x16)[k] = packh2(xr[2 * k], xr[2 * k + 1]);
      }
    }
    __syncthreads();
  }

  // ---------- epilogue: Wo for t = T-1 ----------
  if (tid < 512) {
    int c = tid & 127, q = tid >> 7;
    float s = 0.f;
#pragma unroll
    for (int i = 0; i < 4; ++i)
      s = dot4(wop4[(q * 4 + i) * 128 + c], rp4[q * 4 + i], s);
    wtmp[q * 128 + c] = s;
  }
  __syncthreads();
  if (tid < 128) {
    float o = boL[tid] + wtmp[tid] + wtmp[128 + tid] + wtmp[256 + tid] + wtmp[384 + tid];
    out[((size_t)(T_ - 1) * B_ + b) * I_ + tid] = o;
  }
}

extern "C" void kernel_launch(void* const* d_in, const int* in_sizes, int n_in,
                              void* d_out, int out_size, void* d_ws, size_t ws_size,
                              hipStream_t stream) {
  (void)in_sizes; (void)n_in; (void)out_size;

  const float* x    = (const float*)d_in[0];
  const float* Wc   = (const float*)d_in[1];
  const float* bc   = (const float*)d_in[2];
  const float* Wk   = (const float*)d_in[3];
  const float* bk   = (const float*)d_in[4];
  const float* Wb   = (const float*)d_in[5];
  const float* bbv  = (const float*)d_in[6];
  const float* Wg   = (const float*)d_in[7];
  const float* bg   = (const float*)d_in[8];
  const float* Wsf  = (const float*)d_in[9];
  const float* bsf  = (const float*)d_in[10];
  const float* Wgm  = (const float*)d_in[11];
  const float* bgm  = (const float*)d_in[12];
  const float* We   = (const float*)d_in[13];
  const float* be   = (const float*)d_in[14];
  const float* Wa   = (const float*)d_in[15];
  const float* ba   = (const float*)d_in[16];
  const float* Wo   = (const float*)d_in[17];
  const float* bo   = (const float*)d_in[18];
  const float* mem0 = (const float*)d_in[19];
  const float* ww0  = (const float*)d_in[20];
  const float* rw0  = (const float*)d_in[21];
  const float* rd0  = (const float*)d_in[22];
  float* out = (float*)d_out;
  unsigned* wsu = (unsigned*)d_ws;

  const int useXc = (ws_size >= WS_BYTES_NEEDED) ? 1 : 0;

  ntm_pack<<<dim3(512), dim3(256), 0, stream>>>(Wc, Wk, Wb, Wg, Wsf, Wgm, We, Wa, Wo, wsu);
  if (useXc)
    ntm_xc<<<dim3(T_ * B_ / 16), dim3(256), 0, stream>>>(x, wsu, wsu);
  ntm_main<<<dim3(NB), dim3(NT), 0, stream>>>(x, bc, bk, bbv, bg, bsf, bgm, be, ba, bo,
                                              mem0, ww0, rw0, rd0, wsu, out, useXc);
}

// Round 7
// 2340.198 us; speedup vs baseline: 1.9643x; 1.0268x over previous
//
#include <hip/hip_runtime.h>
#include <math.h>

#define T_ 64
#define B_ 256
#define N_ 256
#define M_ 128
#define H_ 1024
#define I_ 128
#define NB 256
#define NT 1024
#define MSTR 132          // mem row stride (floats)
#define EPSF 1e-8f

// ---- ws layout (uint offsets). Big weights THREAD-MAJOR [k-chunk][col]:
// consecutive lanes read consecutive 16B -> coalesced wave transactions. ----
#define WS_WCX 0                 // [16 k4][1024 h] uint4  (Wc x-part)
#define WS_WCR 65536             // [16 k4][1024 h] uint4  (Wc rd-part)
#define WS_W2P 131072            // [128 k4][512 c] uint4  (Wk0|Wk1|We|Wa)
#define WS_WOP 393216            // [16 k4][128 c]  uint4  (Wo)
#define WS_WSM 401408            // [12 d][512 k2]  uint   (beta,g,gamma,shift)
#define WS_XC  407552            // _Float16 xc[T*B][H] (32 MB)
#define WS_BYTES_NEEDED ((size_t)(407552 + 8388608) * 4)

typedef _Float16 h2_t __attribute__((ext_vector_type(2)));

__device__ __forceinline__ float fdot2(unsigned a, unsigned b, float c) {
  union { unsigned u; h2_t h; } ua, ub;
  ua.u = a; ub.u = b;
  return __builtin_amdgcn_fdot2(ua.h, ub.h, c, false);
}
__device__ __forceinline__ unsigned packh2(float a, float b) {
  union { h2_t h; unsigned u; } v;
  v.h = h2_t{(_Float16)a, (_Float16)b};
  return v.u;
}
__device__ __forceinline__ float dot4(uint4 w, uint4 h, float acc) {
  acc = fdot2(w.x, h.x, acc); acc = fdot2(w.y, h.y, acc);
  acc = fdot2(w.z, h.z, acc); acc = fdot2(w.w, h.w, acc);
  return acc;
}
__device__ __forceinline__ float wave_rsum(float v) {
#pragma unroll
  for (int o = 32; o > 0; o >>= 1) v += __shfl_xor(v, o, 64);
  return v;
}
__device__ __forceinline__ float wave_rmax(float v) {
#pragma unroll
  for (int o = 32; o > 0; o >>= 1) v = fmaxf(v, __shfl_xor(v, o, 64));
  return v;
}

// ============ pack: fp32 -> fp16, thread-major chunked layouts ============
__global__ void ntm_pack(const float* __restrict__ Wc, const float* __restrict__ Wk,
                         const float* __restrict__ Wb, const float* __restrict__ Wg,
                         const float* __restrict__ Wsf, const float* __restrict__ Wgm,
                         const float* __restrict__ We, const float* __restrict__ Wa,
                         const float* __restrict__ Wo,
                         unsigned* __restrict__ wsu)
{
  const int total = 407552;
  for (int i = blockIdx.x * blockDim.x + threadIdx.x; i < total;
       i += gridDim.x * blockDim.x) {
    if (i < 65536) {                       // WCX: q4 = k4*1024 + h
      int jm = i & 3, q4 = i >> 2, k4 = q4 >> 10, h = q4 & 1023;
      int k0 = k4 * 8 + 2 * jm;
      wsu[WS_WCX + i] = packh2(Wc[(size_t)k0 * H_ + h], Wc[(size_t)(k0 + 1) * H_ + h]);
    } else if (i < 131072) {               // WCR: rd-part rows 128..255
      int u = i - 65536;
      int jm = u & 3, q4 = u >> 2, k4 = q4 >> 10, h = q4 & 1023;
      int k0 = 128 + k4 * 8 + 2 * jm;
      wsu[WS_WCR + u] = packh2(Wc[(size_t)k0 * H_ + h], Wc[(size_t)(k0 + 1) * H_ + h]);
    } else if (i < 393216) {               // W2P: q4 = k4*512 + c
      int u = i - 131072;
      int jm = u & 3, q4 = u >> 2, k4 = q4 >> 9, c = q4 & 511;
      int k0 = k4 * 8 + 2 * jm, k1 = k0 + 1;
      float v0, v1;
      if (c < 128)      { v0 = Wk[(size_t)k0 * M_ + c];           v1 = Wk[(size_t)k1 * M_ + c]; }
      else if (c < 256) { v0 = Wk[(size_t)H_ * M_ + (size_t)k0 * M_ + (c - 128)];
                          v1 = Wk[(size_t)H_ * M_ + (size_t)k1 * M_ + (c - 128)]; }
      else if (c < 384) { v0 = We[(size_t)k0 * M_ + (c - 256)];   v1 = We[(size_t)k1 * M_ + (c - 256)]; }
      else              { v0 = Wa[(size_t)k0 * M_ + (c - 384)];   v1 = Wa[(size_t)k1 * M_ + (c - 384)]; }
      wsu[WS_W2P + u] = packh2(v0, v1);
    } else if (i < 401408) {               // WOP: q4 = k4*128 + c
      int u = i - 393216;
      int jm = u & 3, q4 = u >> 2, k4 = q4 >> 7, c = q4 & 127;
      int m0 = k4 * 8 + 2 * jm;
      wsu[WS_WOP + u] = packh2(Wo[(size_t)m0 * I_ + c], Wo[(size_t)(m0 + 1) * I_ + c]);
    } else {                               // WSM: [12 d][512 k2]
      int u = i - 401408, d = u >> 9, k2 = u & 511;
      int k0 = 2 * k2, k1 = 2 * k2 + 1;
      float v0, v1;
      if (d < 2)      { v0 = Wb[d * H_ + k0];        v1 = Wb[d * H_ + k1]; }
      else if (d < 4) { v0 = Wg[(d - 2) * H_ + k0];  v1 = Wg[(d - 2) * H_ + k1]; }
      else if (d < 6) { v0 = Wgm[(d - 4) * H_ + k0]; v1 = Wgm[(d - 4) * H_ + k1]; }
      else if (d < 9) { v0 = Wsf[k0 * 3 + (d - 6)];  v1 = Wsf[k1 * 3 + (d - 6)]; }
      else            { v0 = Wsf[3 * H_ + k0 * 3 + (d - 9)]; v1 = Wsf[3 * H_ + k1 * 3 + (d - 9)]; }
      wsu[WS_WSM + u] = packh2(v0, v1);
    }
  }
}

// ============ xc precompute: xc[t,b,:] = x[t,b,:] @ Wc_x (fp16) ============
__global__ __launch_bounds__(256)
void ntm_xc(const float* __restrict__ x, const unsigned* __restrict__ wsu,
            unsigned* __restrict__ wsout)
{
  __shared__ __align__(16) _Float16 xt[16 * 128];
  const int tid = threadIdx.x;
  const size_t row0 = (size_t)blockIdx.x * 16;
  for (int i = tid; i < 16 * 128; i += 256)
    xt[i] = (_Float16)x[(row0 + (i >> 7)) * I_ + (i & 127)];
  __syncthreads();
  _Float16* xc16 = (_Float16*)(wsout + WS_XC);
  const uint4* xt4 = (const uint4*)xt;
  const uint4* w4 = (const uint4*)(wsu + WS_WCX);
  for (int cq = 0; cq < 4; ++cq) {
    const int col = cq * 256 + tid;
    float acc[16];
#pragma unroll
    for (int r = 0; r < 16; ++r) acc[r] = 0.f;
#pragma unroll 4
    for (int k4 = 0; k4 < 16; ++k4) {
      uint4 w = w4[k4 * 1024 + col];
#pragma unroll
      for (int r = 0; r < 16; ++r)
        acc[r] = dot4(w, xt4[r * 16 + k4], acc[r]);
    }
#pragma unroll
    for (int r = 0; r < 16; ++r)
      xc16[(row0 + r) * H_ + col] = (_Float16)acc[r];
  }
}

// ============ main: one persistent 1024-thread block per batch element ============
// amdgpu_waves_per_eu(4,4): exactly 4 waves/EU (the single LDS-resident block).
// R5/R6 spilled chronically because the allocator kept the default 8-wave/EU
// 64-VGPR budget; this grants ~128 VGPRs.
__global__ __launch_bounds__(NT)
__attribute__((amdgpu_waves_per_eu(4, 4)))
void ntm_main(const float* __restrict__ x,
              const float* __restrict__ bc,  const float* __restrict__ bk,
              const float* __restrict__ bbv, const float* __restrict__ bg,
              const float* __restrict__ bsf, const float* __restrict__ bgm,
              const float* __restrict__ be,  const float* __restrict__ ba,
              const float* __restrict__ bo,
              const float* __restrict__ mem0, const float* __restrict__ ww0,
              const float* __restrict__ rw0,  const float* __restrict__ rd0,
              const unsigned* __restrict__ wsu,
              float* __restrict__ out, int useXc)
{
  __shared__ __align__(16) float mem[N_ * MSTR];     // 135168 B
  __shared__ __align__(16) _Float16 ht16[H_];        // 2048
  __shared__ __align__(16) _Float16 rd16[M_];        // 256
  __shared__ __align__(16) _Float16 x16[M_];         // 256 (fallback)
  __shared__ __align__(16) float prevw[2 * N_];      // ww | rw (final, normalized)
  __shared__ __align__(16) float mnv[N_];
  __shared__ __align__(16) float ksh[2 * M_];
  __shared__ __align__(16) float eah[2 * M_];
  __shared__ __align__(16) float wlog[2 * N_];       // raw cosine (no beta)
  __shared__ __align__(16) float wtmp[2 * N_];       // Wo partials (512 used)
  __shared__ __align__(16) float redU[2048];         // rd part | sq part
  __shared__ __align__(16) float sdots[24];
  __shared__ __align__(16) float scal[32];
  __shared__ __align__(16) float bcL[H_];
  __shared__ __align__(16) float bkL[256];
  __shared__ __align__(16) float beL[128];
  __shared__ __align__(16) float baL[128];
  __shared__ __align__(16) float boL[128];
  __shared__ __align__(16) float sb[16];

  const int tid = threadIdx.x;
  const int b = blockIdx.x;
  const _Float16* xcg = (const _Float16*)(wsu + WS_XC);
  const uint4* wcx4 = (const uint4*)(wsu + WS_WCX);
  const uint4* wcr4 = (const uint4*)(wsu + WS_WCR);
  const uint4* w2p4 = (const uint4*)(wsu + WS_W2P);
  const uint4* wop4 = (const uint4*)(wsu + WS_WOP);
  const uint4* wsm4 = (const uint4*)(wsu + WS_WSM);
  const uint4* rp4 = (const uint4*)rd16;
  const uint4* hp4 = (const uint4*)ht16;

  // ---------- prologue ----------
  for (int i = tid; i < N_ * M_; i += NT)
    mem[(i >> 7) * MSTR + (i & 127)] = mem0[i];
  bcL[tid] = bc[tid];
  if (tid < 256) bkL[tid] = bk[tid];
  if (tid < 128) { beL[tid] = be[tid]; baL[tid] = ba[tid]; boL[tid] = bo[tid]; }
  if (tid < 12) {
    float v;
    if (tid < 2) v = bbv[tid];
    else if (tid < 4) v = bg[tid - 2];
    else if (tid < 6) v = bgm[tid - 4];
    else v = bsf[tid - 6];
    sb[tid] = v;
  }
  if (tid < 512) wlog[tid] = (tid < 256) ? ww0[tid] : rw0[tid - 256];
  __syncthreads();
  if (tid < 256) {
    float s = 0.f;
#pragma unroll 8
    for (int m = 0; m < M_; ++m) { float v = mem[tid * MSTR + m]; s += v * v; }
    mnv[tid] = fmaxf(sqrtf(s), EPSF);
  }
  {
    int wv = tid >> 6, ln = tid & 63;
    if (wv < 2) {
      float l0 = wlog[wv * N_ + ln], l1 = wlog[wv * N_ + 64 + ln],
            l2 = wlog[wv * N_ + 128 + ln], l3 = wlog[wv * N_ + 192 + ln];
      float mx = wave_rmax(fmaxf(fmaxf(l0, l1), fmaxf(l2, l3)));
      float e0 = __expf(l0 - mx), e1 = __expf(l1 - mx), e2 = __expf(l2 - mx), e3 = __expf(l3 - mx);
      float sm = wave_rsum(e0 + e1 + e2 + e3);
      wlog[wv * N_ + ln] = e0; wlog[wv * N_ + 64 + ln] = e1;
      wlog[wv * N_ + 128 + ln] = e2; wlog[wv * N_ + 192 + ln] = e3;
      if (ln == 0) scal[30 + wv] = 1.f / sm;
    }
  }
  __syncthreads();
  if (tid < 512) prevw[tid] = wlog[tid] * scal[30 + (tid >> 8)];
  if (tid < 64)
    ((unsigned*)rd16)[tid] = packh2(rd0[2 * tid], rd0[2 * tid + 1]);
  if (!useXc && tid >= 64 && tid < 128) {
    int k = tid - 64;
    ((unsigned*)x16)[k] = packh2(x[(size_t)b * I_ + 2 * k], x[(size_t)b * I_ + 2 * k + 1]);
  }
  __syncthreads();

  // ---------- time loop ----------
  for (int t = 0; t < T_; ++t) {
    // S1: phase A (h-col per thread, 4 accumulators) + fused Wo partials
    {
      const int j = tid;
      float a0, a1 = 0.f, a2 = 0.f, a3 = 0.f;
      if (useXc) {
        a0 = (float)xcg[((size_t)t * B_ + b) * H_ + j];
      } else {
        a0 = 0.f;
        const uint4* xp4 = (const uint4*)x16;
#pragma unroll
        for (int k4 = 0; k4 < 16; k4 += 4) {
          a0 = dot4(wcx4[k4 * 1024 + j], xp4[k4], a0);
          a1 = dot4(wcx4[(k4 + 1) * 1024 + j], xp4[k4 + 1], a1);
          a2 = dot4(wcx4[(k4 + 2) * 1024 + j], xp4[k4 + 2], a2);
          a3 = dot4(wcx4[(k4 + 3) * 1024 + j], xp4[k4 + 3], a3);
        }
      }
#pragma unroll
      for (int k4 = 0; k4 < 16; k4 += 4) {
        a0 = dot4(wcr4[k4 * 1024 + j], rp4[k4], a0);
        a1 = dot4(wcr4[(k4 + 1) * 1024 + j], rp4[k4 + 1], a1);
        a2 = dot4(wcr4[(k4 + 2) * 1024 + j], rp4[k4 + 2], a2);
        a3 = dot4(wcr4[(k4 + 3) * 1024 + j], rp4[k4 + 3], a3);
      }
      ht16[j] = (_Float16)tanhf(((a0 + a1) + (a2 + a3)) + bcL[j]);
      if (tid < 512) {               // Wo partials (4 k4-chunks each)
        int c = tid & 127, q = tid >> 7;
        float s = 0.f;
#pragma unroll
        for (int i = 0; i < 4; ++i)
          s = dot4(wop4[(q * 4 + i) * 128 + c], rp4[q * 4 + i], s);
        wtmp[q * 128 + c] = s;
      }
    }
    __syncthreads();

    // S3: phase B, in-wave K-half split: wave w -> cols [w*32,w*32+32),
    //     lane: c = w*32+(l&31), khalf = l>>5; combine via shfl_xor(32).
    //     + sdots (waves 10-15) + out-write(t-1) (tid<128)
    {
      const int w = tid >> 6, l = tid & 63;
      const int c = w * 32 + (l & 31);
      const int kk = (l >> 5) * 64;
      float a0 = 0.f, a1 = 0.f, a2 = 0.f, a3 = 0.f;
#pragma unroll 4
      for (int k = 0; k < 64; k += 4) {
        a0 = dot4(w2p4[(size_t)(kk + k) * 512 + c],     hp4[kk + k],     a0);
        a1 = dot4(w2p4[(size_t)(kk + k + 1) * 512 + c], hp4[kk + k + 1], a1);
        a2 = dot4(w2p4[(size_t)(kk + k + 2) * 512 + c], hp4[kk + k + 2], a2);
        a3 = dot4(w2p4[(size_t)(kk + k + 3) * 512 + c], hp4[kk + k + 3], a3);
      }
      float acc = (a0 + a1) + (a2 + a3);
      acc += __shfl_xor(acc, 32, 64);
      if (l < 32) {
        if (c < 256)      ksh[c] = fmaxf(acc + bkL[c], 0.f);
        else if (c < 384) eah[c - 256] = 1.f / (1.f + __expf(-(acc + beL[c - 256])));
        else              eah[c - 256] = 1.f / (1.f + __expf(-(acc + baL[c - 384])));
      }
      if (w >= 10) {                 // 24 half-dots, 4 per wave
#pragma unroll
        for (int i = 0; i < 4; ++i) {
          int hd = (w - 10) * 4 + i;
          int d = hd >> 1, half = hd & 1;
          float s = dot4(wsm4[d * 128 + half * 64 + l], hp4[half * 64 + l], 0.f);
          s = wave_rsum(s);
          if (l == 0) sdots[hd] = s;
        }
      }
      if (tid < 128 && t > 0) {
        float o = boL[tid] + wtmp[tid] + wtmp[128 + tid] + wtmp[256 + tid] + wtmp[384 + tid];
        out[((size_t)(t - 1) * B_ + b) * I_ + tid] = o;
      }
    }
    __syncthreads();

    // S6: cosine, all 16 waves: (h = wv&1, rows nblk*32+(ln&31), M-half = ln>>5),
    //     key-norm computed inline from the same k registers.
    {
      int wv = tid >> 6, ln = tid & 63;
      int h = wv & 1, nblk = wv >> 1;
      int r = nblk * 32 + (ln & 31), mh = ln >> 5;
      const float4* kp = (const float4*)&ksh[h * 128 + mh * 64];
      const float* mrow = &mem[r * MSTR + mh * 64];
      float dot = 0.f, kq = 0.f;
#pragma unroll
      for (int i = 0; i < 16; ++i) {
        float4 kv = kp[i];
        float4 mv = *(const float4*)&mrow[i * 4];
        dot += kv.x * mv.x + kv.y * mv.y + kv.z * mv.z + kv.w * mv.w;
        kq  += kv.x * kv.x + kv.y * kv.y + kv.z * kv.z + kv.w * kv.w;
      }
      dot += __shfl_xor(dot, 32, 64);
      kq  += __shfl_xor(kq, 32, 64);
      if (ln < 32) {
        float kn = fmaxf(sqrtf(kq), EPSF);
        wlog[h * N_ + r] = dot / (kn * mnv[r]);
      }
    }
    __syncthreads();

    // S7: addressing chain, 2 waves (one per head), sequential neighbor calc
    //     to cap live registers (~14 temps).
    if (tid < 128) {
      int h = tid >> 6, ln = tid & 63;
      float Sb = sdots[2 * h] + sdots[2 * h + 1] + sb[h];
      float beta = (Sb > 20.f) ? Sb : log1pf(__expf(Sb));
      float g = 1.f / (1.f + __expf(-(sdots[2 * (2 + h)] + sdots[2 * (2 + h) + 1] + sb[2 + h])));
      float gam = fmaxf(sdots[2 * (4 + h)] + sdots[2 * (4 + h) + 1] + sb[4 + h], 0.f) + 1.f;
      float t0 = sdots[2 * (6 + 3 * h)] + sdots[2 * (6 + 3 * h) + 1] + sb[6 + 3 * h];
      float t1 = sdots[2 * (7 + 3 * h)] + sdots[2 * (7 + 3 * h) + 1] + sb[7 + 3 * h];
      float t2 = sdots[2 * (8 + 3 * h)] + sdots[2 * (8 + 3 * h) + 1] + sb[8 + 3 * h];
      float mx3 = fmaxf(t0, fmaxf(t1, t2));
      float e0s = __expf(t0 - mx3), e1s = __expf(t1 - mx3), e2s = __expf(t2 - mx3);
      float inv3 = 1.f / (e0s + e1s + e2s);
      float s0 = e0s * inv3, s1 = e1s * inv3, s2 = e2s * inv3;
      // softmax(beta*cos)
      float w0 = beta * wlog[h * N_ + ln],        w1 = beta * wlog[h * N_ + 64 + ln];
      float w2 = beta * wlog[h * N_ + 128 + ln],  w3 = beta * wlog[h * N_ + 192 + ln];
      float mx = wave_rmax(fmaxf(fmaxf(w0, w1), fmaxf(w2, w3)));
      w0 = __expf(w0 - mx); w1 = __expf(w1 - mx); w2 = __expf(w2 - mx); w3 = __expf(w3 - mx);
      float inv = 1.f / wave_rsum(w0 + w1 + w2 + w3);
      // interpolate
      w0 = g * w0 * inv + (1.f - g) * prevw[h * N_ + ln];
      w1 = g * w1 * inv + (1.f - g) * prevw[h * N_ + 64 + ln];
      w2 = g * w2 * inv + (1.f - g) * prevw[h * N_ + 128 + ln];
      w3 = g * w3 * inv + (1.f - g) * prevw[h * N_ + 192 + ln];
      // circular shift + sharpen, one row-group at a time
      int lm = (ln + 63) & 63, lp = (ln + 1) & 63;
      float u0, u1, u2, u3;
      {
        float lft = __shfl(w0, lm, 64); float edge = __shfl(w3, 63, 64);
        if (ln == 0) lft = edge;
        float rgt = __shfl(w0, lp, 64); edge = __shfl(w1, 0, 64);
        if (ln == 63) rgt = edge;
        u0 = __powf(s0 * lft + s1 * w0 + s2 * rgt, gam);
      }
      {
        float lft = __shfl(w1, lm, 64); float edge = __shfl(w0, 63, 64);
        if (ln == 0) lft = edge;
        float rgt = __shfl(w1, lp, 64); edge = __shfl(w2, 0, 64);
        if (ln == 63) rgt = edge;
        u1 = __powf(s0 * lft + s1 * w1 + s2 * rgt, gam);
      }
      {
        float lft = __shfl(w2, lm, 64); float edge = __shfl(w1, 63, 64);
        if (ln == 0) lft = edge;
        float rgt = __shfl(w2, lp, 64); edge = __shfl(w3, 0, 64);
        if (ln == 63) rgt = edge;
        u2 = __powf(s0 * lft + s1 * w2 + s2 * rgt, gam);
      }
      {
        float lft = __shfl(w3, lm, 64); float edge = __shfl(w2, 63, 64);
        if (ln == 0) lft = edge;
        float rgt = __shfl(w3, lp, 64); edge = __shfl(w0, 0, 64);
        if (ln == 63) rgt = edge;
        u3 = __powf(s0 * lft + s1 * w3 + s2 * rgt, gam);
      }
      float invs = 1.f / wave_rsum(u0 + u1 + u2 + u3);
      prevw[h * N_ + ln] = u0 * invs;
      prevw[h * N_ + 64 + ln] = u1 * invs;
      prevw[h * N_ + 128 + ln] = u2 * invs;
      prevw[h * N_ + 192 + ln] = u3 * invs;
    }
    __syncthreads();

    // S11: memory update (thread = (row, M-quarter)) + sq partials
    {
      int n = tid & 255, q = tid >> 8;
      float wwn = prevw[n];
      float* mrow = &mem[n * MSTR + q * 32];
      const float4* ep = (const float4*)&eah[q * 32];
      const float4* ap = (const float4*)&eah[128 + q * 32];
      float sq = 0.f;
#pragma unroll
      for (int i = 0; i < 8; ++i) {
        float4 mv = *(float4*)&mrow[i * 4];
        float4 ev = ep[i], av = ap[i];
        mv.x = mv.x * (1.f - wwn * ev.x) + wwn * av.x;
        mv.y = mv.y * (1.f - wwn * ev.y) + wwn * av.y;
        mv.z = mv.z * (1.f - wwn * ev.z) + wwn * av.z;
        mv.w = mv.w * (1.f - wwn * ev.w) + wwn * av.w;
        sq += mv.x * mv.x + mv.y * mv.y + mv.z * mv.z + mv.w * mv.w;
        *(float4*)&mrow[i * 4] = mv;
      }
      redU[1024 + q * 256 + n] = sq;
    }
    __syncthreads();

    // S12: rd partials vectorized over m (tid<256) | mnv finalize (512-767)
    if (tid < 256) {
      int m4 = tid & 31, g = tid >> 5;       // 8 groups of 32 rows
      const float* base = &mem[(g * 32) * MSTR + m4 * 4];
      float4 acc = {0.f, 0.f, 0.f, 0.f};
#pragma unroll 8
      for (int i = 0; i < 32; ++i) {
        float rw = prevw[256 + g * 32 + i];
        float4 mv = *(const float4*)&base[i * MSTR];
        acc.x += rw * mv.x; acc.y += rw * mv.y; acc.z += rw * mv.z; acc.w += rw * mv.w;
      }
      *(float4*)&redU[g * 128 + m4 * 4] = acc;
    } else if (tid >= 512 && tid < 768) {
      int n = tid - 512;
      float s = redU[1024 + n] + redU[1280 + n] + redU[1536 + n] + redU[1792 + n];
      mnv[n] = fmaxf(sqrtf(s), EPSF);
    }
    __syncthreads();

    // S13: rd finalize + pack | next-x pack (fallback)
    {
      if (tid < 64) {
        float r0 = 0.f, r1 = 0.f;
#pragma unroll
        for (int g = 0; g < 8; ++g) {
          r0 += redU[g * 128 + 2 * tid];
          r1 += redU[g * 128 + 2 * tid + 1];
        }
        ((unsigned*)rd16)[tid] = packh2(r0, r1);
      } else if (!useXc && tid >= 768 && tid < 832 && t < T_ - 1) {
        int k = tid - 768;
        const float* xr = &x[((size_t)(t + 1) * B_ + b) * I_];
        ((unsigned*)x16)[k] = packh2(xr[2 * k], xr[2 * k + 1]);
      }
    }
    __syncthreads();
  }

  // ---------- epilogue: Wo for t = T-1 ----------
  if (tid < 512) {
    int c = tid & 127, q = tid >> 7;
    float s = 0.f;
#pragma unroll
    for (int i = 0; i < 4; ++i)
      s = dot4(wop4[(q * 4 + i) * 128 + c], rp4[q * 4 + i], s);
    wtmp[q * 128 + c] = s;
  }
  __syncthreads();
  if (tid < 128) {
    float o = boL[tid] + wtmp[tid] + wtmp[128 + tid] + wtmp[256 + tid] + wtmp[384 + tid];
    out[((size_t)(T_ - 1) * B_ + b) * I_ + tid] = o;
  }
}

extern "C" void kernel_launch(void* const* d_in, const int* in_sizes, int n_in,
                              void* d_out, int out_size, void* d_ws, size_t ws_size,
                              hipStream_t stream) {
  (void)in_sizes; (void)n_in; (void)out_size;

  const float* x    = (const float*)d_in[0];
  const float* Wc   = (const float*)d_in[1];
  const float* bc   = (const float*)d_in[2];
  const float* Wk   = (const float*)d_in[3];
  const float* bk   = (const float*)d_in[4];
  const float* Wb   = (const float*)d_in[5];
  const float* bbv  = (const float*)d_in[6];
  const float* Wg   = (const float*)d_in[7];
  const float* bg   = (const float*)d_in[8];
  const float* Wsf  = (const float*)d_in[9];
  const float* bsf  = (const float*)d_in[10];
  const float* Wgm  = (const float*)d_in[11];
  const float* bgm  = (const float*)d_in[12];
  const float* We   = (const float*)d_in[13];
  const float* be   = (const float*)d_in[14];
  const float* Wa   = (const float*)d_in[15];
  const float* ba   = (const float*)d_in[16];
  const float* Wo   = (const float*)d_in[17];
  const float* bo   = (const float*)d_in[18];
  const float* mem0 = (const float*)d_in[19];
  const float* ww0  = (const float*)d_in[20];
  const float* rw0  = (const float*)d_in[21];
  const float* rd0  = (const float*)d_in[22];
  float* out = (float*)d_out;
  unsigned* wsu = (unsigned*)d_ws;

  const int useXc = (ws_size >= WS_BYTES_NEEDED) ? 1 : 0;

  ntm_pack<<<dim3(512), dim3(256), 0, stream>>>(Wc, Wk, Wb, Wg, Wsf, Wgm, We, Wa, Wo, wsu);
  if (useXc)
    ntm_xc<<<dim3(T_ * B_ / 16), dim3(256), 0, stream>>>(x, wsu, wsu);
  ntm_main<<<dim3(NB), dim3(NT), 0, stream>>>(x, bc, bk, bbv, bg, bsf, bgm, be, ba, bo,
                                              mem0, ww0, rw0, rd0, wsu, out, useXc);
}

// Round 9
// 1407.658 us; speedup vs baseline: 3.2657x; 1.6625x over previous
//
#include <hip/hip_runtime.h>
#include <math.h>

#define T_ 64
#define B_ 256
#define N_ 256
#define M_ 128
#define H_ 1024
#define I_ 128
#define NB 256
#define NT 1024
#define MSTR 132          // mem row stride (floats)
#define EPSF 1e-8f

// ---- ws layout (uint offsets). Big weights THREAD-MAJOR [k-chunk][col]:
// consecutive lanes read consecutive 16B -> coalesced wave transactions. ----
#define WS_WCX 0                 // [16 k4][1024 h] uint4  (Wc x-part)
#define WS_WCR 65536             // [16 k4][1024 h] uint4  (Wc rd-part)
#define WS_W2P 131072            // [128 k4][512 c] uint4  (Wk0|Wk1|We|Wa)
#define WS_WOP 393216            // [16 k4][128 c]  uint4  (Wo)
#define WS_WSM 401408            // [12 d][512 k2]  uint   (beta,g,gamma,shift)
#define WS_XC  407552            // _Float16 xc[T*B][H] (32 MB)
#define WS_BYTES_NEEDED ((size_t)(407552 + 8388608) * 4)

typedef _Float16 h2_t __attribute__((ext_vector_type(2)));

__device__ __forceinline__ float fdot2(unsigned a, unsigned b, float c) {
  union { unsigned u; h2_t h; } ua, ub;
  ua.u = a; ub.u = b;
  return __builtin_amdgcn_fdot2(ua.h, ub.h, c, false);
}
__device__ __forceinline__ unsigned packh2(float a, float b) {
  union { h2_t h; unsigned u; } v;
  v.h = h2_t{(_Float16)a, (_Float16)b};
  return v.u;
}
__device__ __forceinline__ float dot4(uint4 w, uint4 h, float acc) {
  acc = fdot2(w.x, h.x, acc); acc = fdot2(w.y, h.y, acc);
  acc = fdot2(w.z, h.z, acc); acc = fdot2(w.w, h.w, acc);
  return acc;
}
__device__ __forceinline__ float wave_rsum(float v) {
#pragma unroll
  for (int o = 32; o > 0; o >>= 1) v += __shfl_xor(v, o, 64);
  return v;
}
__device__ __forceinline__ float wave_rmax(float v) {
#pragma unroll
  for (int o = 32; o > 0; o >>= 1) v = fmaxf(v, __shfl_xor(v, o, 64));
  return v;
}

// ============ pack: fp32 -> fp16, thread-major chunked layouts ============
__global__ void ntm_pack(const float* __restrict__ Wc, const float* __restrict__ Wk,
                         const float* __restrict__ Wb, const float* __restrict__ Wg,
                         const float* __restrict__ Wsf, const float* __restrict__ Wgm,
                         const float* __restrict__ We, const float* __restrict__ Wa,
                         const float* __restrict__ Wo,
                         unsigned* __restrict__ wsu)
{
  const int total = 407552;
  for (int i = blockIdx.x * blockDim.x + threadIdx.x; i < total;
       i += gridDim.x * blockDim.x) {
    if (i < 65536) {                       // WCX: q4 = k4*1024 + h
      int jm = i & 3, q4 = i >> 2, k4 = q4 >> 10, h = q4 & 1023;
      int k0 = k4 * 8 + 2 * jm;
      wsu[WS_WCX + i] = packh2(Wc[(size_t)k0 * H_ + h], Wc[(size_t)(k0 + 1) * H_ + h]);
    } else if (i < 131072) {               // WCR: rd-part rows 128..255
      int u = i - 65536;
      int jm = u & 3, q4 = u >> 2, k4 = q4 >> 10, h = q4 & 1023;
      int k0 = 128 + k4 * 8 + 2 * jm;
      wsu[WS_WCR + u] = packh2(Wc[(size_t)k0 * H_ + h], Wc[(size_t)(k0 + 1) * H_ + h]);
    } else if (i < 393216) {               // W2P: q4 = k4*512 + c
      int u = i - 131072;
      int jm = u & 3, q4 = u >> 2, k4 = q4 >> 9, c = q4 & 511;
      int k0 = k4 * 8 + 2 * jm, k1 = k0 + 1;
      float v0, v1;
      if (c < 128)      { v0 = Wk[(size_t)k0 * M_ + c];           v1 = Wk[(size_t)k1 * M_ + c]; }
      else if (c < 256) { v0 = Wk[(size_t)H_ * M_ + (size_t)k0 * M_ + (c - 128)];
                          v1 = Wk[(size_t)H_ * M_ + (size_t)k1 * M_ + (c - 128)]; }
      else if (c < 384) { v0 = We[(size_t)k0 * M_ + (c - 256)];   v1 = We[(size_t)k1 * M_ + (c - 256)]; }
      else              { v0 = Wa[(size_t)k0 * M_ + (c - 384)];   v1 = Wa[(size_t)k1 * M_ + (c - 384)]; }
      wsu[WS_W2P + u] = packh2(v0, v1);
    } else if (i < 401408) {               // WOP: q4 = k4*128 + c
      int u = i - 393216;
      int jm = u & 3, q4 = u >> 2, k4 = q4 >> 7, c = q4 & 127;
      int m0 = k4 * 8 + 2 * jm;
      wsu[WS_WOP + u] = packh2(Wo[(size_t)m0 * I_ + c], Wo[(size_t)(m0 + 1) * I_ + c]);
    } else {                               // WSM: [12 d][512 k2]
      int u = i - 401408, d = u >> 9, k2 = u & 511;
      int k0 = 2 * k2, k1 = 2 * k2 + 1;
      float v0, v1;
      if (d < 2)      { v0 = Wb[d * H_ + k0];        v1 = Wb[d * H_ + k1]; }
      else if (d < 4) { v0 = Wg[(d - 2) * H_ + k0];  v1 = Wg[(d - 2) * H_ + k1]; }
      else if (d < 6) { v0 = Wgm[(d - 4) * H_ + k0]; v1 = Wgm[(d - 4) * H_ + k1]; }
      else if (d < 9) { v0 = Wsf[k0 * 3 + (d - 6)];  v1 = Wsf[k1 * 3 + (d - 6)]; }
      else            { v0 = Wsf[3 * H_ + k0 * 3 + (d - 9)]; v1 = Wsf[3 * H_ + k1 * 3 + (d - 9)]; }
      wsu[WS_WSM + u] = packh2(v0, v1);
    }
  }
}

// ============ xc precompute: xc[t,b,:] = x[t,b,:] @ Wc_x (fp16) ============
__global__ __launch_bounds__(256)
void ntm_xc(const float* __restrict__ x, const unsigned* __restrict__ wsu,
            unsigned* __restrict__ wsout)
{
  __shared__ __align__(16) _Float16 xt[16 * 128];
  const int tid = threadIdx.x;
  const size_t row0 = (size_t)blockIdx.x * 16;
  for (int i = tid; i < 16 * 128; i += 256)
    xt[i] = (_Float16)x[(row0 + (i >> 7)) * I_ + (i & 127)];
  __syncthreads();
  _Float16* xc16 = (_Float16*)(wsout + WS_XC);
  const uint4* xt4 = (const uint4*)xt;
  const uint4* w4 = (const uint4*)(wsu + WS_WCX);
  for (int cq = 0; cq < 4; ++cq) {
    const int col = cq * 256 + tid;
    float acc[16];
#pragma unroll
    for (int r = 0; r < 16; ++r) acc[r] = 0.f;
#pragma unroll 4
    for (int k4 = 0; k4 < 16; ++k4) {
      uint4 w = w4[k4 * 1024 + col];
#pragma unroll
      for (int r = 0; r < 16; ++r)
        acc[r] = dot4(w, xt4[r * 16 + k4], acc[r]);
    }
#pragma unroll
    for (int r = 0; r < 16; ++r)
      xc16[(row0 + r) * H_ + col] = (_Float16)acc[r];
  }
}

// ============ main: one persistent 1024-thread block per batch element ============
// NOTE: at NT=1024 this toolchain pins VGPR budget at 64 (R5-R7 measured).
// Every phase below is written to fit 64 VGPRs: 2-accumulator GEMV loops,
// addressing chain split into two low-pressure sub-phases. Wo partials live
// in redU[1024..1535] (lifetime-disjoint from sq partials) to stay under the
// 160 KB LDS limit.
__global__ __launch_bounds__(NT)
void ntm_main(const float* __restrict__ x,
              const float* __restrict__ bc,  const float* __restrict__ bk,
              const float* __restrict__ bbv, const float* __restrict__ bg,
              const float* __restrict__ bsf, const float* __restrict__ bgm,
              const float* __restrict__ be,  const float* __restrict__ ba,
              const float* __restrict__ bo,
              const float* __restrict__ mem0, const float* __restrict__ ww0,
              const float* __restrict__ rw0,  const float* __restrict__ rd0,
              const unsigned* __restrict__ wsu,
              float* __restrict__ out, int useXc)
{
  __shared__ __align__(16) float mem[N_ * MSTR];     // 135168 B
  __shared__ __align__(16) _Float16 ht16[H_];        // 2048
  __shared__ __align__(16) _Float16 rd16[M_];        // 256
  __shared__ __align__(16) _Float16 x16[M_];         // 256 (fallback)
  __shared__ __align__(16) float prevw[2 * N_];      // ww | rw (final, normalized)
  __shared__ __align__(16) float mnv[N_];
  __shared__ __align__(16) float ksh[2 * M_];
  __shared__ __align__(16) float eah[2 * M_];
  __shared__ __align__(16) float wlog[2 * N_];       // raw cosine
  __shared__ __align__(16) float wtmp[2 * N_];       // interp weights
  __shared__ __align__(16) float redU[2048];         // rd part | sq/Wo part
  __shared__ __align__(16) float sdots[24];
  __shared__ __align__(16) float scal[32];
  __shared__ __align__(16) float bcL[H_];
  __shared__ __align__(16) float bkL[256];
  __shared__ __align__(16) float beL[128];
  __shared__ __align__(16) float baL[128];
  __shared__ __align__(16) float boL[128];
  __shared__ __align__(16) float sb[16];

  const int tid = threadIdx.x;
  const int b = blockIdx.x;
  const _Float16* xcg = (const _Float16*)(wsu + WS_XC);
  const uint4* wcx4 = (const uint4*)(wsu + WS_WCX);
  const uint4* wcr4 = (const uint4*)(wsu + WS_WCR);
  const uint4* w2p4 = (const uint4*)(wsu + WS_W2P);
  const uint4* wop4 = (const uint4*)(wsu + WS_WOP);
  const uint4* wsm4 = (const uint4*)(wsu + WS_WSM);
  const uint4* rp4 = (const uint4*)rd16;
  const uint4* hp4 = (const uint4*)ht16;
  float* wop = redU + 1024;          // Wo partials (S1-write, S3-read)

  // ---------- prologue ----------
  for (int i = tid; i < N_ * M_; i += NT)
    mem[(i >> 7) * MSTR + (i & 127)] = mem0[i];
  bcL[tid] = bc[tid];
  if (tid < 256) bkL[tid] = bk[tid];
  if (tid < 128) { beL[tid] = be[tid]; baL[tid] = ba[tid]; boL[tid] = bo[tid]; }
  if (tid < 12) {
    float v;
    if (tid < 2) v = bbv[tid];
    else if (tid < 4) v = bg[tid - 2];
    else if (tid < 6) v = bgm[tid - 4];
    else v = bsf[tid - 6];
    sb[tid] = v;
  }
  if (tid < 512) wlog[tid] = (tid < 256) ? ww0[tid] : rw0[tid - 256];
  __syncthreads();
  if (tid < 256) {
    float s = 0.f;
#pragma unroll 8
    for (int m = 0; m < M_; ++m) { float v = mem[tid * MSTR + m]; s += v * v; }
    mnv[tid] = fmaxf(sqrtf(s), EPSF);
  }
  {
    int wv = tid >> 6, ln = tid & 63;
    if (wv < 2) {
      float l0 = wlog[wv * N_ + ln], l1 = wlog[wv * N_ + 64 + ln],
            l2 = wlog[wv * N_ + 128 + ln], l3 = wlog[wv * N_ + 192 + ln];
      float mx = wave_rmax(fmaxf(fmaxf(l0, l1), fmaxf(l2, l3)));
      float e0 = __expf(l0 - mx), e1 = __expf(l1 - mx), e2 = __expf(l2 - mx), e3 = __expf(l3 - mx);
      float sm = wave_rsum(e0 + e1 + e2 + e3);
      wlog[wv * N_ + ln] = e0; wlog[wv * N_ + 64 + ln] = e1;
      wlog[wv * N_ + 128 + ln] = e2; wlog[wv * N_ + 192 + ln] = e3;
      if (ln == 0) scal[30 + wv] = 1.f / sm;
    }
  }
  __syncthreads();
  if (tid < 512) prevw[tid] = wlog[tid] * scal[30 + (tid >> 8)];
  if (tid < 64)
    ((unsigned*)rd16)[tid] = packh2(rd0[2 * tid], rd0[2 * tid + 1]);
  if (!useXc && tid >= 64 && tid < 128) {
    int k = tid - 64;
    ((unsigned*)x16)[k] = packh2(x[(size_t)b * I_ + 2 * k], x[(size_t)b * I_ + 2 * k + 1]);
  }
  __syncthreads();

  // ---------- time loop (7 syncs/step) ----------
  for (int t = 0; t < T_; ++t) {
    // S1: phase A (h-col per thread, 2 accumulators) + fused Wo partials
    {
      const int j = tid;
      float a0, a1 = 0.f;
      if (useXc) {
        a0 = (float)xcg[((size_t)t * B_ + b) * H_ + j];
      } else {
        a0 = 0.f;
        const uint4* xp4 = (const uint4*)x16;
#pragma unroll 4
        for (int k4 = 0; k4 < 16; k4 += 2) {
          a0 = dot4(wcx4[k4 * 1024 + j], xp4[k4], a0);
          a1 = dot4(wcx4[(k4 + 1) * 1024 + j], xp4[k4 + 1], a1);
        }
      }
#pragma unroll 4
      for (int k4 = 0; k4 < 16; k4 += 2) {
        a0 = dot4(wcr4[k4 * 1024 + j], rp4[k4], a0);
        a1 = dot4(wcr4[(k4 + 1) * 1024 + j], rp4[k4 + 1], a1);
      }
      ht16[j] = (_Float16)tanhf((a0 + a1) + bcL[j]);
      if (tid < 512) {               // Wo partials (4 k4-chunks each)
        int c = tid & 127, q = tid >> 7;
        float s = 0.f;
#pragma unroll
        for (int i = 0; i < 4; ++i)
          s = dot4(wop4[(q * 4 + i) * 128 + c], rp4[q * 4 + i], s);
        wop[q * 128 + c] = s;
      }
    }
    __syncthreads();

    // S3: phase B, in-wave K-half split (2 accumulators): wave w -> cols
    //     [w*32, w*32+32); lane: c = w*32+(l&31), khalf = l>>5; shfl_xor(32).
    //     + sdots (waves 10-15) + out-write(t-1) (tid<128)
    {
      const int w = tid >> 6, l = tid & 63;
      const int c = w * 32 + (l & 31);
      const int kk = (l >> 5) * 64;
      float a0 = 0.f, a1 = 0.f;
#pragma unroll 2
      for (int k = 0; k < 64; k += 2) {
        a0 = dot4(w2p4[(size_t)(kk + k) * 512 + c],     hp4[kk + k],     a0);
        a1 = dot4(w2p4[(size_t)(kk + k + 1) * 512 + c], hp4[kk + k + 1], a1);
      }
      float acc = a0 + a1;
      acc += __shfl_xor(acc, 32, 64);
      float outv = 0.f;
      if (tid < 128 && t > 0)
        outv = boL[tid] + wop[tid] + wop[128 + tid] + wop[256 + tid] + wop[384 + tid];
      if (l < 32) {
        if (c < 256)      ksh[c] = fmaxf(acc + bkL[c], 0.f);
        else if (c < 384) eah[c - 256] = 1.f / (1.f + __expf(-(acc + beL[c - 256])));
        else              eah[c - 256] = 1.f / (1.f + __expf(-(acc + baL[c - 384])));
      }
      if (w >= 10) {                 // 24 half-dots, 4 per wave
#pragma unroll
        for (int i = 0; i < 4; ++i) {
          int hd = (w - 10) * 4 + i;
          int d = hd >> 1, half = hd & 1;
          float s = dot4(wsm4[d * 128 + half * 64 + l], hp4[half * 64 + l], 0.f);
          s = wave_rsum(s);
          if (l == 0) sdots[hd] = s;
        }
      }
      if (tid < 128 && t > 0)
        out[((size_t)(t - 1) * B_ + b) * I_ + tid] = outv;
    }
    __syncthreads();

    // S6: cosine, all 16 waves; key-norm inline from the same registers.
    {
      int wv = tid >> 6, ln = tid & 63;
      int h = wv & 1, nblk = wv >> 1;
      int r = nblk * 32 + (ln & 31), mh = ln >> 5;
      const float4* kp = (const float4*)&ksh[h * 128 + mh * 64];
      const float* mrow = &mem[r * MSTR + mh * 64];
      float dot = 0.f, kq = 0.f;
#pragma unroll
      for (int i = 0; i < 16; ++i) {
        float4 kv = kp[i];
        float4 mv = *(const float4*)&mrow[i * 4];
        dot += kv.x * mv.x + kv.y * mv.y + kv.z * mv.z + kv.w * mv.w;
        kq  += kv.x * kv.x + kv.y * kv.y + kv.z * kv.z + kv.w * kv.w;
      }
      dot += __shfl_xor(dot, 32, 64);
      kq  += __shfl_xor(kq, 32, 64);
      if (ln < 32) {
        float kn = fmaxf(sqrtf(kq), EPSF);
        wlog[h * N_ + r] = dot / (kn * mnv[r]);
      }
    }
    __syncthreads();

    // S7: addressing, 2 waves (one per head), two low-pressure sub-phases.
    //     Sub-phase 1: scalars + content softmax + interpolate -> wtmp (LDS).
    //     Sub-phase 2: circular shift (LDS neighbor reads, intra-wave only —
    //     no __syncthreads needed) + sharpen + normalize -> prevw.
    if (tid < 128) {
      int h = tid >> 6, ln = tid & 63;
      float Sb = sdots[2 * h] + sdots[2 * h + 1] + sb[h];
      float beta = (Sb > 20.f) ? Sb : log1pf(__expf(Sb));
      float g = 1.f / (1.f + __expf(-(sdots[2 * (2 + h)] + sdots[2 * (2 + h) + 1] + sb[2 + h])));
      float gam = fmaxf(sdots[2 * (4 + h)] + sdots[2 * (4 + h) + 1] + sb[4 + h], 0.f) + 1.f;
      float t0 = sdots[2 * (6 + 3 * h)] + sdots[2 * (6 + 3 * h) + 1] + sb[6 + 3 * h];
      float t1 = sdots[2 * (7 + 3 * h)] + sdots[2 * (7 + 3 * h) + 1] + sb[7 + 3 * h];
      float t2 = sdots[2 * (8 + 3 * h)] + sdots[2 * (8 + 3 * h) + 1] + sb[8 + 3 * h];
      float mx3 = fmaxf(t0, fmaxf(t1, t2));
      float e0s = __expf(t0 - mx3), e1s = __expf(t1 - mx3), e2s = __expf(t2 - mx3);
      float inv3 = 1.f / (e0s + e1s + e2s);
      float s0 = e0s * inv3, s1 = e1s * inv3, s2 = e2s * inv3;
      // content softmax + interpolate -> wtmp
      {
        float w0 = beta * wlog[h * N_ + ln],        float_w1 = beta * wlog[h * N_ + 64 + ln];
        float w2 = beta * wlog[h * N_ + 128 + ln],  w3 = beta * wlog[h * N_ + 192 + ln];
        float w1 = float_w1;
        float mx = wave_rmax(fmaxf(fmaxf(w0, w1), fmaxf(w2, w3)));
        w0 = __expf(w0 - mx); w1 = __expf(w1 - mx); w2 = __expf(w2 - mx); w3 = __expf(w3 - mx);
        float inv = 1.f / wave_rsum(w0 + w1 + w2 + w3);
        float gi = 1.f - g;
        wtmp[h * N_ + ln]        = g * w0 * inv + gi * prevw[h * N_ + ln];
        wtmp[h * N_ + 64 + ln]   = g * w1 * inv + gi * prevw[h * N_ + 64 + ln];
        wtmp[h * N_ + 128 + ln]  = g * w2 * inv + gi * prevw[h * N_ + 128 + ln];
        wtmp[h * N_ + 192 + ln]  = g * w3 * inv + gi * prevw[h * N_ + 192 + ln];
      }
      // circular shift + sharpen + normalize (intra-wave LDS dependency only)
      {
        float u0, u1, u2, u3;
#pragma unroll
        for (int j = 0; j < 4; ++j) {
          int n = j * 64 + ln;
          float v = s0 * wtmp[h * N_ + ((n + 255) & 255)]
                  + s1 * wtmp[h * N_ + n]
                  + s2 * wtmp[h * N_ + ((n + 1) & 255)];
          v = __powf(v, gam);
          if (j == 0) u0 = v; else if (j == 1) u1 = v; else if (j == 2) u2 = v; else u3 = v;
        }
        float invs = 1.f / wave_rsum(u0 + u1 + u2 + u3);
        prevw[h * N_ + ln]       = u0 * invs;
        prevw[h * N_ + 64 + ln]  = u1 * invs;
        prevw[h * N_ + 128 + ln] = u2 * invs;
        prevw[h * N_ + 192 + ln] = u3 * invs;
      }
    }
    __syncthreads();

    // S11: memory update (thread = (row, M-quarter)) + sq partials
    {
      int n = tid & 255, q = tid >> 8;
      float wwn = prevw[n];
      float* mrow = &mem[n * MSTR + q * 32];
      const float4* ep = (const float4*)&eah[q * 32];
      const float4* ap = (const float4*)&eah[128 + q * 32];
      float sq = 0.f;
#pragma unroll
      for (int i = 0; i < 8; ++i) {
        float4 mv = *(float4*)&mrow[i * 4];
        float4 ev = ep[i], av = ap[i];
        mv.x = mv.x * (1.f - wwn * ev.x) + wwn * av.x;
        mv.y = mv.y * (1.f - wwn * ev.y) + wwn * av.y;
        mv.z = mv.z * (1.f - wwn * ev.z) + wwn * av.z;
        mv.w = mv.w * (1.f - wwn * ev.w) + wwn * av.w;
        sq += mv.x * mv.x + mv.y * mv.y + mv.z * mv.z + mv.w * mv.w;
        *(float4*)&mrow[i * 4] = mv;
      }
      redU[1024 + q * 256 + n] = sq;
    }
    __syncthreads();

    // S12: rd partials vectorized over m (tid<256) | mnv finalize (512-767)
    if (tid < 256) {
      int m4 = tid & 31, g = tid >> 5;       // 8 groups of 32 rows
      const float* base = &mem[(g * 32) * MSTR + m4 * 4];
      float4 acc = {0.f, 0.f, 0.f, 0.f};
#pragma unroll 8
      for (int i = 0; i < 32; ++i) {
        float rw = prevw[256 + g * 32 + i];
        float4 mv = *(const float4*)&base[i * MSTR];
        acc.x += rw * mv.x; acc.y += rw * mv.y; acc.z += rw * mv.z; acc.w += rw * mv.w;
      }
      *(float4*)&redU[g * 128 + m4 * 4] = acc;
    } else if (tid >= 512 && tid < 768) {
      int n = tid - 512;
      float s = redU[1024 + n] + redU[1280 + n] + redU[1536 + n] + redU[1792 + n];
      mnv[n] = fmaxf(sqrtf(s), EPSF);
    }
    __syncthreads();

    // S13: rd finalize + pack | next-x pack (fallback)
    {
      if (tid < 64) {
        float r0 = 0.f, r1 = 0.f;
#pragma unroll
        for (int g = 0; g < 8; ++g) {
          r0 += redU[g * 128 + 2 * tid];
          r1 += redU[g * 128 + 2 * tid + 1];
        }
        ((unsigned*)rd16)[tid] = packh2(r0, r1);
      } else if (!useXc && tid >= 768 && tid < 832 && t < T_ - 1) {
        int k = tid - 768;
        const float* xr = &x[((size_t)(t + 1) * B_ + b) * I_];
        ((unsigned*)x16)[k] = packh2(xr[2 * k], xr[2 * k + 1]);
      }
    }
    __syncthreads();
  }

  // ---------- epilogue: Wo for t = T-1 ----------
  if (tid < 512) {
    int c = tid & 127, q = tid >> 7;
    float s = 0.f;
#pragma unroll
    for (int i = 0; i < 4; ++i)
      s = dot4(wop4[(q * 4 + i) * 128 + c], rp4[q * 4 + i], s);
    wop[q * 128 + c] = s;
  }
  __syncthreads();
  if (tid < 128) {
    float o = boL[tid] + wop[tid] + wop[128 + tid] + wop[256 + tid] + wop[384 + tid];
    out[((size_t)(T_ - 1) * B_ + b) * I_ + tid] = o;
  }
}

extern "C" void kernel_launch(void* const* d_in, const int* in_sizes, int n_in,
                              void* d_out, int out_size, void* d_ws, size_t ws_size,
                              hipStream_t stream) {
  (void)in_sizes; (void)n_in; (void)out_size;

  const float* x    = (const float*)d_in[0];
  const float* Wc   = (const float*)d_in[1];
  const float* bc   = (const float*)d_in[2];
  const float* Wk   = (const float*)d_in[3];
  const float* bk   = (const float*)d_in[4];
  const float* Wb   = (const float*)d_in[5];
  const float* bbv  = (const float*)d_in[6];
  const float* Wg   = (const float*)d_in[7];
  const float* bg   = (const float*)d_in[8];
  const float* Wsf  = (const float*)d_in[9];
  const float* bsf  = (const float*)d_in[10];
  const float* Wgm  = (const float*)d_in[11];
  const float* bgm  = (const float*)d_in[12];
  const float* We   = (const float*)d_in[13];
  const float* be   = (const float*)d_in[14];
  const float* Wa   = (const float*)d_in[15];
  const float* ba   = (const float*)d_in[16];
  const float* Wo   = (const float*)d_in[17];
  const float* bo   = (const float*)d_in[18];
  const float* mem0 = (const float*)d_in[19];
  const float* ww0  = (const float*)d_in[20];
  const float* rw0  = (const float*)d_in[21];
  const float* rd0  = (const float*)d_in[22];
  float* out = (float*)d_out;
  unsigned* wsu = (unsigned*)d_ws;

  const int useXc = (ws_size >= WS_BYTES_NEEDED) ? 1 : 0;

  ntm_pack<<<dim3(512), dim3(256), 0, stream>>>(Wc, Wk, Wb, Wg, Wsf, Wgm, We, Wa, Wo, wsu);
  if (useXc)
    ntm_xc<<<dim3(T_ * B_ / 16), dim3(256), 0, stream>>>(x, wsu, wsu);
  ntm_main<<<dim3(NB), dim3(NT), 0, stream>>>(x, bc, bk, bbv, bg, bsf, bgm, be, ba, bo,
                                              mem0, ww0, rw0, rd0, wsu, out, useXc);
}